// Round 12
// baseline (1323.956 us; speedup 1.0000x reference)
//
#include <hip/hip_runtime.h>
#include <hip/hip_cooperative_groups.h>
namespace cg = cooperative_groups;

#define NN 100000
#define EE 1600000
#define DD 64
#define CC 10
#define GG 512
#define LL 5
#define NPAD 100352            // 392*256
#define N64 (NN * DD)
#define NB 392                 // coarse buckets (256 nodes each)
#define PCH 4096               // edges per partition block
#define BCAP 6144              // per-bucket LDS capacity (mean 4082, >30 sigma)
#define SC 8                   // BN stats shadow copies
#define PREPG 1563             // (NN+63)/64
#define L1TILES 1563           // layer1 virtual 64-row tiles
#define CHUNKS 782             // layer2/3 128-row chunks (782*128 >= NN)

typedef short bf16x8 __attribute__((ext_vector_type(8)));
typedef float f32x4  __attribute__((ext_vector_type(4)));
union U16 { uint4 u; bf16x8 h; };

__device__ __forceinline__ float bits2f(unsigned int b) { return __uint_as_float(b); }
__device__ __forceinline__ float bf2f(unsigned short s) { return __uint_as_float((unsigned int)s << 16); }
__device__ __forceinline__ unsigned short f2bf_rne(float v) {
    unsigned int b = __float_as_uint(v);
    return (unsigned short)((b + 0x7fffu + ((b >> 16) & 1u)) >> 16);
}
__device__ __forceinline__ void unpack8(uint4 u, float* f) {
    f[0] = bits2f(u.x << 16); f[1] = bits2f(u.x & 0xffff0000u);
    f[2] = bits2f(u.y << 16); f[3] = bits2f(u.y & 0xffff0000u);
    f[4] = bits2f(u.z << 16); f[5] = bits2f(u.z & 0xffff0000u);
    f[6] = bits2f(u.w << 16); f[7] = bits2f(u.w & 0xffff0000u);
}
__device__ __forceinline__ uint4 pack8(const float* f) {
    uint4 u;
    u.x = (unsigned int)f2bf_rne(f[0]) | ((unsigned int)f2bf_rne(f[1]) << 16);
    u.y = (unsigned int)f2bf_rne(f[2]) | ((unsigned int)f2bf_rne(f[3]) << 16);
    u.z = (unsigned int)f2bf_rne(f[4]) | ((unsigned int)f2bf_rne(f[5]) << 16);
    u.w = (unsigned int)f2bf_rne(f[6]) | ((unsigned int)f2bf_rne(f[7]) << 16);
    return u;
}
__device__ __forceinline__ void acc8(uint4 u, float* a) {
    float t[8];
    unpack8(u, t);
    #pragma unroll
    for (int k = 0; k < 8; ++k) a[k] += t[k];
}

// ======== fused prep: x->bf16 + layer-0 pool | W transpose | edge hist ========
__global__ __launch_bounds__(256) void prep_all_k(
    const float* __restrict__ x, const int* __restrict__ batch,
    unsigned short* __restrict__ hbuf, float* __restrict__ pooled,
    const float* __restrict__ W1, const float* __restrict__ W2,
    unsigned short* __restrict__ wt,
    const int* __restrict__ ei, int* __restrict__ bh)
{
    __shared__ int cnt[NB];
    const int bid = blockIdx.x;
    const int t = threadIdx.x;
    if (bid < PREPG) {
        int f = t & 63;
        int q = t >> 6;
        int n0 = bid * 64 + q * 16;
        int nmax = NN - n0; if (nmax > 16) nmax = 16;
        float acc = 0.f;
        int curg = -1;
        #pragma unroll 4
        for (int i = 0; i < nmax; ++i) {
            int n = n0 + i;
            int g = batch[n];
            if (g != curg) {
                if (curg >= 0) atomicAdd(&pooled[(size_t)curg * DD + f], acc);
                acc = 0.f; curg = g;
            }
            float v = x[(size_t)n * DD + f];
            hbuf[(size_t)n * DD + f] = f2bf_rne(v);
            acc += v;
        }
        if (curg >= 0) atomicAdd(&pooled[(size_t)curg * DD + f], acc);
    } else if (bid < PREPG + 8) {
        int mat = bid - PREPG;
        const float* src = (mat < 4) ? (W1 + (size_t)mat * 4096)
                                     : (W2 + (size_t)(mat - 4) * 4096);
        for (int idx = t; idx < 4096; idx += 256) {
            int c = idx >> 6, k = idx & 63;
            wt[(size_t)mat * 4096 + c * 64 + k] = f2bf_rne(src[k * 64 + c]);
        }
    } else {
        int hid = bid - PREPG - 8;          // 0..511
        for (int i = t; i < NB; i += 256) cnt[i] = 0;
        __syncthreads();
        for (int e = hid * 256 + t; e < EE; e += 512 * 256)
            atomicAdd(&cnt[ei[EE + e] >> 8], 1);
        __syncthreads();
        for (int i = t; i < NB; i += 256)
            if (cnt[i]) atomicAdd(&bh[i], cnt[i]);
    }
}

// ================= coarse scan =================
__global__ __launch_bounds__(512) void bscan_k(const int* __restrict__ bh,
                                               int* __restrict__ bo,
                                               int* __restrict__ bcur) {
    __shared__ int s[512];
    int t = threadIdx.x;
    int v = (t < NB) ? bh[t] : 0;
    s[t] = v;
    __syncthreads();
    for (int d = 1; d < 512; d <<= 1) {
        int a = (t >= d) ? s[t - d] : 0;
        __syncthreads();
        s[t] += a;
        __syncthreads();
    }
    int excl = s[t] - v;
    if (t < NB) { bo[t] = excl; bcur[t] = excl; }
    if (t == NB - 1) bo[NB] = excl + v;
}

// ============ partition edges into bucket-contiguous staging ============
// stage entry: src (bits 0..16) | dst-local-in-bucket (bits 17..24)
__global__ __launch_bounds__(256) void partition_k(const int* __restrict__ ei,
                                                   int* __restrict__ bcur,
                                                   unsigned int* __restrict__ stage) {
    __shared__ int hist[NB];
    __shared__ int base[NB];
    __shared__ int gbase[NB];
    __shared__ int cnt2[NB];
    __shared__ int scanbuf[512];
    __shared__ unsigned int pairs[PCH];
    __shared__ unsigned short pbkt[PCH];
    int t = threadIdx.x;
    int e0 = blockIdx.x * PCH;
    int nE = EE - e0; if (nE > PCH) nE = PCH;

    for (int i = t; i < NB; i += 256) { hist[i] = 0; cnt2[i] = 0; }
    __syncthreads();

    int mys[16], myd[16];
    #pragma unroll
    for (int i = 0; i < 16; ++i) {
        int idx = i * 256 + t;
        if (idx < nE) {
            mys[i] = ei[e0 + idx];
            myd[i] = ei[EE + e0 + idx];
            atomicAdd(&hist[myd[i] >> 8], 1);
        } else myd[i] = -1;
    }
    __syncthreads();

    scanbuf[t]       = (t < NB) ? hist[t] : 0;
    scanbuf[t + 256] = (t + 256 < NB) ? hist[t + 256] : 0;
    __syncthreads();
    for (int d = 1; d < 512; d <<= 1) {
        int a0 = (t >= d) ? scanbuf[t - d] : 0;
        int a1 = ((t + 256) >= d) ? scanbuf[t + 256 - d] : 0;
        __syncthreads();
        scanbuf[t] += a0;
        scanbuf[t + 256] += a1;
        __syncthreads();
    }
    if (t < NB)       base[t]       = scanbuf[t] - hist[t];
    if (t + 256 < NB) base[t + 256] = scanbuf[t + 256] - hist[t + 256];
    __syncthreads();

    #pragma unroll
    for (int i = 0; i < 16; ++i) {
        if (myd[i] >= 0) {
            int b = myd[i] >> 8;
            int p = base[b] + atomicAdd(&cnt2[b], 1);
            pairs[p] = (unsigned)mys[i] | ((unsigned)(myd[i] & 255) << 17);
            pbkt[p] = (unsigned short)b;
        }
    }
    __syncthreads();
    for (int i = t; i < NB; i += 256)
        if (hist[i]) gbase[i] = atomicAdd(&bcur[i], hist[i]);
    __syncthreads();
    for (int p = t; p < nE; p += 256) {
        int b = pbkt[p];
        stage[gbase[b] + (p - base[b])] = pairs[p];
    }
}

// ============ per-bucket CSR: adj + offs, all in LDS ============
__global__ __launch_bounds__(256) void bucket_csr_k(const unsigned int* __restrict__ stage,
                                                    const int* __restrict__ bo,
                                                    int* __restrict__ adj,
                                                    int* __restrict__ offs) {
    __shared__ int deg[256];
    __shared__ int sb[256];
    __shared__ int nb_[256];
    __shared__ int c2[256];
    __shared__ int loc[BCAP];
    int b = blockIdx.x;
    int s0 = bo[b], s1 = bo[b + 1];
    int cnt = s1 - s0;
    int t = threadIdx.x;

    deg[t] = 0;
    __syncthreads();
    for (int i = t; i < cnt; i += 256) atomicAdd(&deg[(stage[s0 + i] >> 17) & 255], 1);
    __syncthreads();
    sb[t] = deg[t];
    __syncthreads();
    for (int d = 1; d < 256; d <<= 1) {
        int a = (t >= d) ? sb[t - d] : 0;
        __syncthreads();
        sb[t] += a;
        __syncthreads();
    }
    int nbase = sb[t] - deg[t];
    nb_[t] = nbase;
    c2[t] = 0;
    offs[b * 256 + t] = s0 + nbase;
    __syncthreads();

    if (cnt <= BCAP) {
        for (int i = t; i < cnt; i += 256) {
            unsigned int pr = stage[s0 + i];
            int ln = (pr >> 17) & 255;
            int p = nb_[ln] + atomicAdd(&c2[ln], 1);
            loc[p] = (int)(pr & 0x1FFFF);
        }
        __syncthreads();
        for (int i = t; i < cnt; i += 256) adj[s0 + i] = loc[i];
    } else {            // statistically unreachable fallback
        for (int i = t; i < cnt; i += 256) {
            unsigned int pr = stage[s0 + i];
            int ln = (pr >> 17) & 255;
            int p = nb_[ln] + atomicAdd(&c2[ln], 1);
            adj[s0 + p] = (int)(pr & 0x1FFFF);
        }
    }
}

// ========== cooperative mega-kernel: 4 x (L1 gather+GEMM1 | L2 BN+GEMM2 | L3 BN+pool) + readout ==========
// R12: replaces 13 dispatches (12 global-barrier boundaries at ~8us each) with
// 12 grid.sync()s in ONE kernel. Phase work is claimed via per-phase global
// atomic counters (work-conserving -> no static-stride stragglers). Phase
// bodies are the verified R11 code; W-fragments + BN scale/shift hoisted once
// per layer. launch_bounds(512,8) pins VGPR<=64 for co-residency.
__global__ __launch_bounds__(512, 8) void gin_coop_k(
    unsigned short* __restrict__ hbuf,       // read by L1, rewritten by L3
    const int* __restrict__ adj,
    const int* __restrict__ offs,
    const float* __restrict__ epsArr,
    const unsigned short* __restrict__ wt,
    const float* __restrict__ b1,
    const float* __restrict__ g1,
    const float* __restrict__ be1,
    const float* __restrict__ b2,
    const float* __restrict__ gout,
    const float* __restrict__ beout,
    unsigned short* __restrict__ z1b,
    unsigned short* __restrict__ z2b,
    float* __restrict__ pooled,
    float* __restrict__ stats1,
    float* __restrict__ stats2,
    const int* __restrict__ batch,
    int* __restrict__ ctr,
    const float* __restrict__ Wp,
    const float* __restrict__ bp,
    float* __restrict__ out)
{
    cg::grid_group grid = cg::this_grid();
    __shared__ unsigned short aLDS[64 * 64];   // 8KB, XOR-swizzled 16B units
    __shared__ float ssS[128];
    __shared__ int vbS;
    const int t = threadIdx.x;
    const int lane = t & 63;
    const int w = t >> 6;          // 0..7
    const int n15 = lane & 15;
    const int quad = lane >> 4;
    const int c8 = lane & 7;
    const int bid = blockIdx.x;

    for (int l = 0; l < LL - 1; ++l) {
        const unsigned short* wt1 = wt + (size_t)l * 4096;
        const unsigned short* wt2 = wt + (size_t)(4 + l) * 4096;
        const float* bias1 = b1 + l * DD;
        const float* bias2 = b2 + l * DD;
        const float epsv = 1.0f + epsArr[l];

        // ================= phase L1: gather + GEMM1 + stats1 =================
        // B fragments for this wave's 2 column tiles: once per layer
        const int rt = w & 3;
        const int cb = (w >> 2) * 2;
        U16 bfr1[2][2];
        #pragma unroll
        for (int ci = 0; ci < 2; ++ci)
            #pragma unroll
            for (int ks = 0; ks < 2; ++ks)
                bfr1[ci][ks].u = *(const uint4*)(wt1 + (size_t)((cb + ci) * 16 + n15) * 64 + ks * 32 + quad * 8);

        for (;;) {
            __syncthreads();                       // protects aLDS + vbS reuse
            if (t == 0) vbS = atomicAdd(&ctr[l * 3], 1);
            __syncthreads();
            const int vb = vbS;
            if (vb >= L1TILES) break;
            if (vb < SC && t < 128) stats2[vb * 128 + t] = 0.f;

            // ---- gather (R8 adj-prefetch pipeline) ----
            {
                int lr = w * 8 + (lane >> 3);
                int n = vb * 64 + lr;
                float acc[8] = {0.f,0.f,0.f,0.f,0.f,0.f,0.f,0.f};
                if (n < NN) {
                    uint4 a = *(const uint4*)(hbuf + (size_t)n * DD + c8 * 8);
                    unpack8(a, acc);
                    #pragma unroll
                    for (int k = 0; k < 8; ++k) acc[k] *= epsv;
                    int j = offs[n], end = offs[n + 1];
                    if (j < end) {
                        int e1 = end - 1;
                        int a0 = adj[j];
                        int a1 = adj[(j + 1 < end) ? j + 1 : e1];
                        int a2 = adj[(j + 2 < end) ? j + 2 : e1];
                        int a3 = adj[(j + 3 < end) ? j + 3 : e1];
                        #pragma unroll 1
                        while (j < end) {
                            uint4 v0 = *(const uint4*)(hbuf + (size_t)a0 * DD + c8 * 8);
                            uint4 v1 = *(const uint4*)(hbuf + (size_t)a1 * DD + c8 * 8);
                            uint4 v2 = *(const uint4*)(hbuf + (size_t)a2 * DD + c8 * 8);
                            uint4 v3 = *(const uint4*)(hbuf + (size_t)a3 * DD + c8 * 8);
                            int jn = j + 4;
                            int b0 = adj[(jn     < end) ? jn     : e1];
                            int b1i = adj[(jn + 1 < end) ? jn + 1 : e1];
                            int b2i = adj[(jn + 2 < end) ? jn + 2 : e1];
                            int b3i = adj[(jn + 3 < end) ? jn + 3 : e1];
                            int rem = end - j;
                            acc8(v0, acc);
                            if (rem > 1) acc8(v1, acc);
                            if (rem > 2) acc8(v2, acc);
                            if (rem > 3) acc8(v3, acc);
                            a0 = b0; a1 = b1i; a2 = b2i; a3 = b3i;
                            j = jn;
                        }
                    }
                }
                int pu = c8 ^ (lr & 7);
                *(uint4*)(aLDS + lr * 64 + pu * 8) = pack8(acc);
            }
            __syncthreads();                       // A-rows in LDS are cross-wave

            U16 afr[2];
            int lr2 = rt * 16 + n15;
            #pragma unroll
            for (int ks = 0; ks < 2; ++ks) {
                int pu = (ks * 4 + quad) ^ (lr2 & 7);
                afr[ks].u = *(const uint4*)(aLDS + lr2 * 64 + pu * 8);
            }

            const int rowg0 = vb * 64 + rt * 16;
            const int copy = vb & (SC - 1);
            #pragma unroll
            for (int ci = 0; ci < 2; ++ci) {
                int ct = cb + ci;
                f32x4 acc = {0.f, 0.f, 0.f, 0.f};
                acc = __builtin_amdgcn_mfma_f32_16x16x32_bf16(afr[0].h, bfr1[ci][0].h, acc, 0, 0, 0);
                acc = __builtin_amdgcn_mfma_f32_16x16x32_bf16(afr[1].h, bfr1[ci][1].h, acc, 0, 0, 0);
                int col = ct * 16 + n15;
                float bcol = bias1[col];
                float s = 0.f, ss = 0.f;
                #pragma unroll
                for (int r = 0; r < 4; ++r) {
                    int rg = rowg0 + quad * 4 + r;
                    float v = acc[r] + bcol;
                    if (rg < NN) {
                        z1b[(size_t)rg * DD + col] = f2bf_rne(v);
                        s += v;
                        ss = fmaf(v, v, ss);
                    }
                }
                s  += __shfl_xor(s, 16, 64);  s  += __shfl_xor(s, 32, 64);
                ss += __shfl_xor(ss, 16, 64); ss += __shfl_xor(ss, 32, 64);
                if (lane < 16) {
                    atomicAdd(&stats1[copy * 128 + ct * 16 + lane], s);
                    atomicAdd(&stats1[copy * 128 + 64 + ct * 16 + lane], ss);
                }
            }
        }
        grid.sync();

        // ================= phase L2: BN1 + GEMM2 + stats2 =================
        if (t < 64) {
            float S = 0.f, SS = 0.f;
            #pragma unroll
            for (int c = 0; c < SC; ++c) { S += stats1[c * 128 + t]; SS += stats1[c * 128 + 64 + t]; }
            float inv_n = 1.0f / (float)NN;
            float mean = S * inv_n;
            float var  = SS * inv_n - mean * mean;
            float sc = g1[l * DD + t] * rsqrtf(var + 1e-5f);
            ssS[t] = sc;
            ssS[64 + t] = be1[l * DD + t] - sc * mean;
        }
        __syncthreads();

        U16 bfr2[4][2];
        #pragma unroll
        for (int ct = 0; ct < 4; ++ct)
            #pragma unroll
            for (int ks = 0; ks < 2; ++ks)
                bfr2[ct][ks].u = *(const uint4*)(wt2 + (size_t)(ct * 16 + n15) * 64 + ks * 32 + quad * 8);

        float sacc[4]  = {0.f, 0.f, 0.f, 0.f};
        float ssacc[4] = {0.f, 0.f, 0.f, 0.f};
        for (;;) {
            __syncthreads();
            if (t == 0) vbS = atomicAdd(&ctr[l * 3 + 1], 1);
            __syncthreads();
            const int ch = vbS;
            if (ch >= CHUNKS) break;
            const int rowg0 = ch * 128 + (w >> 2) * 64 + (w & 3) * 16;
            int arow = rowg0 + n15;
            int arowc = (arow < NN) ? arow : (NN - 1);
            uint4 raw[2];
            #pragma unroll
            for (int ks = 0; ks < 2; ++ks)
                raw[ks] = *(const uint4*)(z1b + (size_t)arowc * DD + ks * 32 + quad * 8);

            U16 afr[2];
            #pragma unroll
            for (int ks = 0; ks < 2; ++ks) {
                float f[8];
                unpack8(raw[ks], f);
                int k0 = ks * 32 + quad * 8;
                #pragma unroll
                for (int jj = 0; jj < 8; ++jj)
                    f[jj] = fmaxf(fmaf(ssS[k0 + jj], f[jj], ssS[64 + k0 + jj]), 0.f);
                afr[ks].u = pack8(f);
            }

            #pragma unroll
            for (int ct = 0; ct < 4; ++ct) {
                f32x4 acc = {0.f, 0.f, 0.f, 0.f};
                acc = __builtin_amdgcn_mfma_f32_16x16x32_bf16(afr[0].h, bfr2[ct][0].h, acc, 0, 0, 0);
                acc = __builtin_amdgcn_mfma_f32_16x16x32_bf16(afr[1].h, bfr2[ct][1].h, acc, 0, 0, 0);
                int col = ct * 16 + n15;
                float bcol = bias2[col];
                #pragma unroll
                for (int r = 0; r < 4; ++r) {
                    int rg = rowg0 + quad * 4 + r;
                    float v = acc[r] + bcol;
                    if (rg < NN) {
                        z2b[(size_t)rg * DD + col] = f2bf_rne(v);
                        sacc[ct] += v;
                        ssacc[ct] = fmaf(v, v, ssacc[ct]);
                    }
                }
            }
        }
        {
            const int copy = bid & (SC - 1);
            #pragma unroll
            for (int ct = 0; ct < 4; ++ct) {
                float s = sacc[ct], ss = ssacc[ct];
                s  += __shfl_xor(s, 16, 64);  s  += __shfl_xor(s, 32, 64);
                ss += __shfl_xor(ss, 16, 64); ss += __shfl_xor(ss, 32, 64);
                if (lane < 16) {
                    atomicAdd(&stats2[copy * 128 + ct * 16 + lane], s);
                    atomicAdd(&stats2[copy * 128 + 64 + ct * 16 + lane], ss);
                }
            }
        }
        grid.sync();

        // ================= phase L3: BN2 + ReLU + hb write + pool =================
        if (t < 64) {
            float S = 0.f, SS = 0.f;
            #pragma unroll
            for (int c = 0; c < SC; ++c) { S += stats2[c * 128 + t]; SS += stats2[c * 128 + 64 + t]; }
            float inv_n = 1.0f / (float)NN;
            float mean = S * inv_n;
            float var  = SS * inv_n - mean * mean;
            float sc = gout[l * DD + t] * rsqrtf(var + 1e-5f);
            ssS[t] = sc;
            ssS[64 + t] = beout[l * DD + t] - sc * mean;
        }
        __syncthreads();
        float* pl = pooled + (size_t)(l + 1) * GG * DD;
        const int f = t & 63;
        const int q = t >> 6;
        const float scv = ssS[f], shv = ssS[64 + f];
        for (;;) {
            __syncthreads();
            if (t == 0) vbS = atomicAdd(&ctr[l * 3 + 2], 1);
            __syncthreads();
            const int ch = vbS;
            if (ch >= CHUNKS) break;
            if (ch < SC && t < 128) stats1[ch * 128 + t] = 0.f;   // for next layer's L1
            int n0 = ch * 128 + q * 16;
            int nmax = NN - n0; if (nmax > 16) nmax = 16;
            float acc = 0.f;
            int curg = -1;
            #pragma unroll 4
            for (int i = 0; i < nmax; ++i) {
                int n = n0 + i;
                int g = batch[n];
                if (g != curg) {
                    if (curg >= 0) atomicAdd(&pl[(size_t)curg * DD + f], acc);
                    acc = 0.f; curg = g;
                }
                float v = bf2f(z2b[(size_t)n * DD + f]);
                v = fmaxf(fmaf(scv, v, shv), 0.f);
                hbuf[(size_t)n * DD + f] = f2bf_rne(v);
                acc += v;
            }
            if (curg >= 0) atomicAdd(&pl[(size_t)curg * DD + f], acc);
        }
        grid.sync();
    }

    // ================= readout =================
    int gc = bid * 512 + t;
    if (gc < GG * CC) {
        int g = gc / CC, c = gc - g * CC;
        float acc = 0.f;
        for (int l = 0; l < LL; ++l) {
            acc += bp[l * CC + c];
            const float* p  = pooled + ((size_t)l * GG + g) * DD;
            const float* wv = Wp + (size_t)l * DD * CC + c;
            #pragma unroll 8
            for (int ff = 0; ff < DD; ++ff) acc = fmaf(p[ff], wv[ff * CC], acc);
        }
        out[gc] = acc;
    }
}

extern "C" void kernel_launch(void* const* d_in, const int* in_sizes, int n_in,
                              void* d_out, int out_size, void* d_ws, size_t ws_size,
                              hipStream_t stream) {
    const float* x     = (const float*)d_in[0];
    const int*   ei    = (const int*)d_in[1];
    const int*   batch = (const int*)d_in[2];
    const float* eps   = (const float*)d_in[3];
    const float* W1    = (const float*)d_in[4];
    const float* b1    = (const float*)d_in[5];
    const float* g1    = (const float*)d_in[6];
    const float* be1   = (const float*)d_in[7];
    const float* W2    = (const float*)d_in[8];
    const float* b2    = (const float*)d_in[9];
    const float* gout  = (const float*)d_in[10];
    const float* beout = (const float*)d_in[11];
    const float* Wp    = (const float*)d_in[12];
    const float* bp    = (const float*)d_in[13];
    float* out = (float*)d_out;

    // ---- workspace layout (16B-aligned sections; bh+ctr adjacent to pooled
    //      so one memset covers bh+ctr+pooled+stats) ----
    unsigned int* stage = (unsigned int*)d_ws;          // EE*4
    int* adj   = (int*)(stage + EE);                    // EE*4
    int* offs  = adj + EE;                              // (NPAD+256)
    int* bo    = offs + NPAD + 256;                     // 400
    int* bcur  = bo + 400;                              // 400
    int* bh    = bcur + 400;                            // 400
    int* ctr   = bh + 400;                              // 16 phase counters
    float* pooled = (float*)(ctr + 16);                 // LL*GG*DD
    float* stats1 = pooled + (size_t)LL * GG * DD;      // SC*128
    float* stats2 = stats1 + SC * 128;                  // SC*128
    unsigned short* hb  = (unsigned short*)(stats2 + SC * 128);
    unsigned short* z1b = hb + N64;
    unsigned short* z2b = z1b + N64;
    unsigned short* wt  = z2b + N64;                    // 8*4096

    // ---- single memset: bh + ctr + pooled + stats1 + stats2 ----
    hipMemsetAsync(bh, 0, (400 + 16 + (size_t)LL * GG * DD + 2 * SC * 128) * sizeof(int), stream);
    // ---- fused prep (x->bf16 + pool0 | W^T | edge hist) ----
    prep_all_k<<<PREPG + 8 + 512, 256, 0, stream>>>(x, batch, hb, pooled, W1, W2, wt, ei, bh);
    bscan_k<<<1, 512, 0, stream>>>(bh, bo, bcur);
    partition_k<<<(EE + PCH - 1) / PCH, 256, 0, stream>>>(ei, bcur, stage);
    bucket_csr_k<<<NB, 256, 0, stream>>>(stage, bo, adj, offs);

    // ---- cooperative mega-kernel: all 4 layers + readout ----
    static int gridBlocks = 0;
    if (gridBlocks == 0) {
        int dev = 0; hipGetDevice(&dev);
        int cus = 256;
        hipDeviceGetAttribute(&cus, hipDeviceAttributeMultiprocessorCount, dev);
        int mpb = 1;
        hipOccupancyMaxActiveBlocksPerMultiprocessor(&mpb, gin_coop_k, 512, 0);
        gridBlocks = mpb * cus;
        if (gridBlocks > 1024) gridBlocks = 1024;
        if (gridBlocks < 256)  gridBlocks = 256;
    }
    unsigned short* hbp = hb;
    void* cargs[] = {
        (void*)&hbp, (void*)&adj, (void*)&offs, (void*)&eps, (void*)&wt,
        (void*)&b1, (void*)&g1, (void*)&be1, (void*)&b2, (void*)&gout,
        (void*)&beout, (void*)&z1b, (void*)&z2b, (void*)&pooled,
        (void*)&stats1, (void*)&stats2, (void*)&batch, (void*)&ctr,
        (void*)&Wp, (void*)&bp, (void*)&out
    };
    hipLaunchCooperativeKernel((void*)gin_coop_k, dim3(gridBlocks), dim3(512),
                               cargs, 0, stream);
}

// Round 13
// 969.096 us; speedup vs baseline: 1.3662x; 1.3662x over previous
//
#include <hip/hip_runtime.h>
#include <hip/hip_cooperative_groups.h>
namespace cg = cooperative_groups;

#define NN 100000
#define EE 1600000
#define DD 64
#define CC 10
#define GG 512
#define LL 5
#define NPAD 100352            // 392*256
#define N64 (NN * DD)
#define NB 392                 // coarse buckets (256 nodes each)
#define PCH 4096               // edges per partition block
#define BCAP 6144              // per-bucket LDS capacity (mean 4082, >30 sigma)
#define SC 8                   // BN stats shadow copies
#define PREPG 1563             // (NN+63)/64
#define L1TILES 1563           // layer1 virtual 64-row tiles
#define CHUNKS 782             // layer2/3 128-row chunks (782*128 >= NN)

typedef short bf16x8 __attribute__((ext_vector_type(8)));
typedef float f32x4  __attribute__((ext_vector_type(4)));
union U16 { uint4 u; bf16x8 h; };

__device__ __forceinline__ float bits2f(unsigned int b) { return __uint_as_float(b); }
__device__ __forceinline__ float bf2f(unsigned short s) { return __uint_as_float((unsigned int)s << 16); }
__device__ __forceinline__ unsigned short f2bf_rne(float v) {
    unsigned int b = __float_as_uint(v);
    return (unsigned short)((b + 0x7fffu + ((b >> 16) & 1u)) >> 16);
}
__device__ __forceinline__ void unpack8(uint4 u, float* f) {
    f[0] = bits2f(u.x << 16); f[1] = bits2f(u.x & 0xffff0000u);
    f[2] = bits2f(u.y << 16); f[3] = bits2f(u.y & 0xffff0000u);
    f[4] = bits2f(u.z << 16); f[5] = bits2f(u.z & 0xffff0000u);
    f[6] = bits2f(u.w << 16); f[7] = bits2f(u.w & 0xffff0000u);
}
__device__ __forceinline__ uint4 pack8(const float* f) {
    uint4 u;
    u.x = (unsigned int)f2bf_rne(f[0]) | ((unsigned int)f2bf_rne(f[1]) << 16);
    u.y = (unsigned int)f2bf_rne(f[2]) | ((unsigned int)f2bf_rne(f[3]) << 16);
    u.z = (unsigned int)f2bf_rne(f[4]) | ((unsigned int)f2bf_rne(f[5]) << 16);
    u.w = (unsigned int)f2bf_rne(f[6]) | ((unsigned int)f2bf_rne(f[7]) << 16);
    return u;
}
__device__ __forceinline__ void acc8(uint4 u, float* a) {
    float t[8];
    unpack8(u, t);
    #pragma unroll
    for (int k = 0; k < 8; ++k) a[k] += t[k];
}

// ======== fused prep: x->bf16 + layer-0 pool | W transpose | edge hist ========
__global__ __launch_bounds__(256) void prep_all_k(
    const float* __restrict__ x, const int* __restrict__ batch,
    unsigned short* __restrict__ hbuf, float* __restrict__ pooled,
    const float* __restrict__ W1, const float* __restrict__ W2,
    unsigned short* __restrict__ wt,
    const int* __restrict__ ei, int* __restrict__ bh)
{
    __shared__ int cnt[NB];
    const int bid = blockIdx.x;
    const int t = threadIdx.x;
    if (bid < PREPG) {
        int f = t & 63;
        int q = t >> 6;
        int n0 = bid * 64 + q * 16;
        int nmax = NN - n0; if (nmax > 16) nmax = 16;
        float acc = 0.f;
        int curg = -1;
        #pragma unroll 4
        for (int i = 0; i < nmax; ++i) {
            int n = n0 + i;
            int g = batch[n];
            if (g != curg) {
                if (curg >= 0) atomicAdd(&pooled[(size_t)curg * DD + f], acc);
                acc = 0.f; curg = g;
            }
            float v = x[(size_t)n * DD + f];
            hbuf[(size_t)n * DD + f] = f2bf_rne(v);
            acc += v;
        }
        if (curg >= 0) atomicAdd(&pooled[(size_t)curg * DD + f], acc);
    } else if (bid < PREPG + 8) {
        int mat = bid - PREPG;
        const float* src = (mat < 4) ? (W1 + (size_t)mat * 4096)
                                     : (W2 + (size_t)(mat - 4) * 4096);
        for (int idx = t; idx < 4096; idx += 256) {
            int c = idx >> 6, k = idx & 63;
            wt[(size_t)mat * 4096 + c * 64 + k] = f2bf_rne(src[k * 64 + c]);
        }
    } else {
        int hid = bid - PREPG - 8;          // 0..511
        for (int i = t; i < NB; i += 256) cnt[i] = 0;
        __syncthreads();
        for (int e = hid * 256 + t; e < EE; e += 512 * 256)
            atomicAdd(&cnt[ei[EE + e] >> 8], 1);
        __syncthreads();
        for (int i = t; i < NB; i += 256)
            if (cnt[i]) atomicAdd(&bh[i], cnt[i]);
    }
}

// ================= coarse scan =================
__global__ __launch_bounds__(512) void bscan_k(const int* __restrict__ bh,
                                               int* __restrict__ bo,
                                               int* __restrict__ bcur) {
    __shared__ int s[512];
    int t = threadIdx.x;
    int v = (t < NB) ? bh[t] : 0;
    s[t] = v;
    __syncthreads();
    for (int d = 1; d < 512; d <<= 1) {
        int a = (t >= d) ? s[t - d] : 0;
        __syncthreads();
        s[t] += a;
        __syncthreads();
    }
    int excl = s[t] - v;
    if (t < NB) { bo[t] = excl; bcur[t] = excl; }
    if (t == NB - 1) bo[NB] = excl + v;
}

// ============ partition edges into bucket-contiguous staging ============
// stage entry: src (bits 0..16) | dst-local-in-bucket (bits 17..24)
__global__ __launch_bounds__(256) void partition_k(const int* __restrict__ ei,
                                                   int* __restrict__ bcur,
                                                   unsigned int* __restrict__ stage) {
    __shared__ int hist[NB];
    __shared__ int base[NB];
    __shared__ int gbase[NB];
    __shared__ int cnt2[NB];
    __shared__ int scanbuf[512];
    __shared__ unsigned int pairs[PCH];
    __shared__ unsigned short pbkt[PCH];
    int t = threadIdx.x;
    int e0 = blockIdx.x * PCH;
    int nE = EE - e0; if (nE > PCH) nE = PCH;

    for (int i = t; i < NB; i += 256) { hist[i] = 0; cnt2[i] = 0; }
    __syncthreads();

    int mys[16], myd[16];
    #pragma unroll
    for (int i = 0; i < 16; ++i) {
        int idx = i * 256 + t;
        if (idx < nE) {
            mys[i] = ei[e0 + idx];
            myd[i] = ei[EE + e0 + idx];
            atomicAdd(&hist[myd[i] >> 8], 1);
        } else myd[i] = -1;
    }
    __syncthreads();

    scanbuf[t]       = (t < NB) ? hist[t] : 0;
    scanbuf[t + 256] = (t + 256 < NB) ? hist[t + 256] : 0;
    __syncthreads();
    for (int d = 1; d < 512; d <<= 1) {
        int a0 = (t >= d) ? scanbuf[t - d] : 0;
        int a1 = ((t + 256) >= d) ? scanbuf[t + 256 - d] : 0;
        __syncthreads();
        scanbuf[t] += a0;
        scanbuf[t + 256] += a1;
        __syncthreads();
    }
    if (t < NB)       base[t]       = scanbuf[t] - hist[t];
    if (t + 256 < NB) base[t + 256] = scanbuf[t + 256] - hist[t + 256];
    __syncthreads();

    #pragma unroll
    for (int i = 0; i < 16; ++i) {
        if (myd[i] >= 0) {
            int b = myd[i] >> 8;
            int p = base[b] + atomicAdd(&cnt2[b], 1);
            pairs[p] = (unsigned)mys[i] | ((unsigned)(myd[i] & 255) << 17);
            pbkt[p] = (unsigned short)b;
        }
    }
    __syncthreads();
    for (int i = t; i < NB; i += 256)
        if (hist[i]) gbase[i] = atomicAdd(&bcur[i], hist[i]);
    __syncthreads();
    for (int p = t; p < nE; p += 256) {
        int b = pbkt[p];
        stage[gbase[b] + (p - base[b])] = pairs[p];
    }
}

// ============ per-bucket CSR: adj + offs, all in LDS ============
__global__ __launch_bounds__(256) void bucket_csr_k(const unsigned int* __restrict__ stage,
                                                    const int* __restrict__ bo,
                                                    int* __restrict__ adj,
                                                    int* __restrict__ offs) {
    __shared__ int deg[256];
    __shared__ int sb[256];
    __shared__ int nb_[256];
    __shared__ int c2[256];
    __shared__ int loc[BCAP];
    int b = blockIdx.x;
    int s0 = bo[b], s1 = bo[b + 1];
    int cnt = s1 - s0;
    int t = threadIdx.x;

    deg[t] = 0;
    __syncthreads();
    for (int i = t; i < cnt; i += 256) atomicAdd(&deg[(stage[s0 + i] >> 17) & 255], 1);
    __syncthreads();
    sb[t] = deg[t];
    __syncthreads();
    for (int d = 1; d < 256; d <<= 1) {
        int a = (t >= d) ? sb[t - d] : 0;
        __syncthreads();
        sb[t] += a;
        __syncthreads();
    }
    int nbase = sb[t] - deg[t];
    nb_[t] = nbase;
    c2[t] = 0;
    offs[b * 256 + t] = s0 + nbase;
    __syncthreads();

    if (cnt <= BCAP) {
        for (int i = t; i < cnt; i += 256) {
            unsigned int pr = stage[s0 + i];
            int ln = (pr >> 17) & 255;
            int p = nb_[ln] + atomicAdd(&c2[ln], 1);
            loc[p] = (int)(pr & 0x1FFFF);
        }
        __syncthreads();
        for (int i = t; i < cnt; i += 256) adj[s0 + i] = loc[i];
    } else {            // statistically unreachable fallback
        for (int i = t; i < cnt; i += 256) {
            unsigned int pr = stage[s0 + i];
            int ln = (pr >> 17) & 255;
            int p = nb_[ln] + atomicAdd(&c2[ln], 1);
            adj[s0 + p] = (int)(pr & 0x1FFFF);
        }
    }
}

// ========== cooperative mega-kernel: 4 x (L1 | L2 | L3) + readout ==========
// R12 post-mortem: launch_bounds(512,8) capped VGPR at 64 < union of phase
// needs -> allocator spilled the hot-loop state to scratch (VGPR_Count=32,
// WRITE 150->575MB, all pipes idle, dur = bytes/590GB/s). R13: (512,4) ->
// VGPR cap 128 (est. need ~80-110). Co-residency 2 blocks/CU = 16 waves/CU;
// occupancy query sizes the grid. Everything else identical to R12.
__global__ __launch_bounds__(512, 4) void gin_coop_k(
    unsigned short* __restrict__ hbuf,       // read by L1, rewritten by L3
    const int* __restrict__ adj,
    const int* __restrict__ offs,
    const float* __restrict__ epsArr,
    const unsigned short* __restrict__ wt,
    const float* __restrict__ b1,
    const float* __restrict__ g1,
    const float* __restrict__ be1,
    const float* __restrict__ b2,
    const float* __restrict__ gout,
    const float* __restrict__ beout,
    unsigned short* __restrict__ z1b,
    unsigned short* __restrict__ z2b,
    float* __restrict__ pooled,
    float* __restrict__ stats1,
    float* __restrict__ stats2,
    const int* __restrict__ batch,
    int* __restrict__ ctr,
    const float* __restrict__ Wp,
    const float* __restrict__ bp,
    float* __restrict__ out)
{
    cg::grid_group grid = cg::this_grid();
    __shared__ unsigned short aLDS[64 * 64];   // 8KB, XOR-swizzled 16B units
    __shared__ float ssS[128];
    __shared__ int vbS;
    const int t = threadIdx.x;
    const int lane = t & 63;
    const int w = t >> 6;          // 0..7
    const int n15 = lane & 15;
    const int quad = lane >> 4;
    const int c8 = lane & 7;
    const int bid = blockIdx.x;

    for (int l = 0; l < LL - 1; ++l) {
        const unsigned short* wt1 = wt + (size_t)l * 4096;
        const unsigned short* wt2 = wt + (size_t)(4 + l) * 4096;
        const float* bias1 = b1 + l * DD;
        const float* bias2 = b2 + l * DD;
        const float epsv = 1.0f + epsArr[l];

        // ================= phase L1: gather + GEMM1 + stats1 =================
        const int rt = w & 3;
        const int cb = (w >> 2) * 2;
        U16 bfr1[2][2];
        #pragma unroll
        for (int ci = 0; ci < 2; ++ci)
            #pragma unroll
            for (int ks = 0; ks < 2; ++ks)
                bfr1[ci][ks].u = *(const uint4*)(wt1 + (size_t)((cb + ci) * 16 + n15) * 64 + ks * 32 + quad * 8);

        for (;;) {
            __syncthreads();                       // protects aLDS + vbS reuse
            if (t == 0) vbS = atomicAdd(&ctr[l * 3], 1);
            __syncthreads();
            const int vb = vbS;
            if (vb >= L1TILES) break;
            if (vb < SC && t < 128) stats2[vb * 128 + t] = 0.f;

            // ---- gather (R8 adj-prefetch pipeline) ----
            {
                int lr = w * 8 + (lane >> 3);
                int n = vb * 64 + lr;
                float acc[8] = {0.f,0.f,0.f,0.f,0.f,0.f,0.f,0.f};
                if (n < NN) {
                    uint4 a = *(const uint4*)(hbuf + (size_t)n * DD + c8 * 8);
                    unpack8(a, acc);
                    #pragma unroll
                    for (int k = 0; k < 8; ++k) acc[k] *= epsv;
                    int j = offs[n], end = offs[n + 1];
                    if (j < end) {
                        int e1 = end - 1;
                        int a0 = adj[j];
                        int a1 = adj[(j + 1 < end) ? j + 1 : e1];
                        int a2 = adj[(j + 2 < end) ? j + 2 : e1];
                        int a3 = adj[(j + 3 < end) ? j + 3 : e1];
                        #pragma unroll 1
                        while (j < end) {
                            uint4 v0 = *(const uint4*)(hbuf + (size_t)a0 * DD + c8 * 8);
                            uint4 v1 = *(const uint4*)(hbuf + (size_t)a1 * DD + c8 * 8);
                            uint4 v2 = *(const uint4*)(hbuf + (size_t)a2 * DD + c8 * 8);
                            uint4 v3 = *(const uint4*)(hbuf + (size_t)a3 * DD + c8 * 8);
                            int jn = j + 4;
                            int b0 = adj[(jn     < end) ? jn     : e1];
                            int b1i = adj[(jn + 1 < end) ? jn + 1 : e1];
                            int b2i = adj[(jn + 2 < end) ? jn + 2 : e1];
                            int b3i = adj[(jn + 3 < end) ? jn + 3 : e1];
                            int rem = end - j;
                            acc8(v0, acc);
                            if (rem > 1) acc8(v1, acc);
                            if (rem > 2) acc8(v2, acc);
                            if (rem > 3) acc8(v3, acc);
                            a0 = b0; a1 = b1i; a2 = b2i; a3 = b3i;
                            j = jn;
                        }
                    }
                }
                int pu = c8 ^ (lr & 7);
                *(uint4*)(aLDS + lr * 64 + pu * 8) = pack8(acc);
            }
            __syncthreads();                       // A-rows in LDS are cross-wave

            U16 afr[2];
            int lr2 = rt * 16 + n15;
            #pragma unroll
            for (int ks = 0; ks < 2; ++ks) {
                int pu = (ks * 4 + quad) ^ (lr2 & 7);
                afr[ks].u = *(const uint4*)(aLDS + lr2 * 64 + pu * 8);
            }

            const int rowg0 = vb * 64 + rt * 16;
            const int copy = vb & (SC - 1);
            #pragma unroll
            for (int ci = 0; ci < 2; ++ci) {
                int ct = cb + ci;
                f32x4 acc = {0.f, 0.f, 0.f, 0.f};
                acc = __builtin_amdgcn_mfma_f32_16x16x32_bf16(afr[0].h, bfr1[ci][0].h, acc, 0, 0, 0);
                acc = __builtin_amdgcn_mfma_f32_16x16x32_bf16(afr[1].h, bfr1[ci][1].h, acc, 0, 0, 0);
                int col = ct * 16 + n15;
                float bcol = bias1[col];
                float s = 0.f, ss = 0.f;
                #pragma unroll
                for (int r = 0; r < 4; ++r) {
                    int rg = rowg0 + quad * 4 + r;
                    float v = acc[r] + bcol;
                    if (rg < NN) {
                        z1b[(size_t)rg * DD + col] = f2bf_rne(v);
                        s += v;
                        ss = fmaf(v, v, ss);
                    }
                }
                s  += __shfl_xor(s, 16, 64);  s  += __shfl_xor(s, 32, 64);
                ss += __shfl_xor(ss, 16, 64); ss += __shfl_xor(ss, 32, 64);
                if (lane < 16) {
                    atomicAdd(&stats1[copy * 128 + ct * 16 + lane], s);
                    atomicAdd(&stats1[copy * 128 + 64 + ct * 16 + lane], ss);
                }
            }
        }
        grid.sync();

        // ================= phase L2: BN1 + GEMM2 + stats2 =================
        if (t < 64) {
            float S = 0.f, SS = 0.f;
            #pragma unroll
            for (int c = 0; c < SC; ++c) { S += stats1[c * 128 + t]; SS += stats1[c * 128 + 64 + t]; }
            float inv_n = 1.0f / (float)NN;
            float mean = S * inv_n;
            float var  = SS * inv_n - mean * mean;
            float sc = g1[l * DD + t] * rsqrtf(var + 1e-5f);
            ssS[t] = sc;
            ssS[64 + t] = be1[l * DD + t] - sc * mean;
        }
        __syncthreads();

        U16 bfr2[4][2];
        #pragma unroll
        for (int ct = 0; ct < 4; ++ct)
            #pragma unroll
            for (int ks = 0; ks < 2; ++ks)
                bfr2[ct][ks].u = *(const uint4*)(wt2 + (size_t)(ct * 16 + n15) * 64 + ks * 32 + quad * 8);

        float sacc[4]  = {0.f, 0.f, 0.f, 0.f};
        float ssacc[4] = {0.f, 0.f, 0.f, 0.f};
        for (;;) {
            __syncthreads();
            if (t == 0) vbS = atomicAdd(&ctr[l * 3 + 1], 1);
            __syncthreads();
            const int ch = vbS;
            if (ch >= CHUNKS) break;
            const int rowg0 = ch * 128 + (w >> 2) * 64 + (w & 3) * 16;
            int arow = rowg0 + n15;
            int arowc = (arow < NN) ? arow : (NN - 1);
            uint4 raw[2];
            #pragma unroll
            for (int ks = 0; ks < 2; ++ks)
                raw[ks] = *(const uint4*)(z1b + (size_t)arowc * DD + ks * 32 + quad * 8);

            U16 afr[2];
            #pragma unroll
            for (int ks = 0; ks < 2; ++ks) {
                float f[8];
                unpack8(raw[ks], f);
                int k0 = ks * 32 + quad * 8;
                #pragma unroll
                for (int jj = 0; jj < 8; ++jj)
                    f[jj] = fmaxf(fmaf(ssS[k0 + jj], f[jj], ssS[64 + k0 + jj]), 0.f);
                afr[ks].u = pack8(f);
            }

            #pragma unroll
            for (int ct = 0; ct < 4; ++ct) {
                f32x4 acc = {0.f, 0.f, 0.f, 0.f};
                acc = __builtin_amdgcn_mfma_f32_16x16x32_bf16(afr[0].h, bfr2[ct][0].h, acc, 0, 0, 0);
                acc = __builtin_amdgcn_mfma_f32_16x16x32_bf16(afr[1].h, bfr2[ct][1].h, acc, 0, 0, 0);
                int col = ct * 16 + n15;
                float bcol = bias2[col];
                #pragma unroll
                for (int r = 0; r < 4; ++r) {
                    int rg = rowg0 + quad * 4 + r;
                    float v = acc[r] + bcol;
                    if (rg < NN) {
                        z2b[(size_t)rg * DD + col] = f2bf_rne(v);
                        sacc[ct] += v;
                        ssacc[ct] = fmaf(v, v, ssacc[ct]);
                    }
                }
            }
        }
        {
            const int copy = bid & (SC - 1);
            #pragma unroll
            for (int ct = 0; ct < 4; ++ct) {
                float s = sacc[ct], ss = ssacc[ct];
                s  += __shfl_xor(s, 16, 64);  s  += __shfl_xor(s, 32, 64);
                ss += __shfl_xor(ss, 16, 64); ss += __shfl_xor(ss, 32, 64);
                if (lane < 16) {
                    atomicAdd(&stats2[copy * 128 + ct * 16 + lane], s);
                    atomicAdd(&stats2[copy * 128 + 64 + ct * 16 + lane], ss);
                }
            }
        }
        grid.sync();

        // ================= phase L3: BN2 + ReLU + hb write + pool =================
        if (t < 64) {
            float S = 0.f, SS = 0.f;
            #pragma unroll
            for (int c = 0; c < SC; ++c) { S += stats2[c * 128 + t]; SS += stats2[c * 128 + 64 + t]; }
            float inv_n = 1.0f / (float)NN;
            float mean = S * inv_n;
            float var  = SS * inv_n - mean * mean;
            float sc = gout[l * DD + t] * rsqrtf(var + 1e-5f);
            ssS[t] = sc;
            ssS[64 + t] = beout[l * DD + t] - sc * mean;
        }
        __syncthreads();
        float* pl = pooled + (size_t)(l + 1) * GG * DD;
        const int f = t & 63;
        const int q = t >> 6;
        const float scv = ssS[f], shv = ssS[64 + f];
        for (;;) {
            __syncthreads();
            if (t == 0) vbS = atomicAdd(&ctr[l * 3 + 2], 1);
            __syncthreads();
            const int ch = vbS;
            if (ch >= CHUNKS) break;
            if (ch < SC && t < 128) stats1[ch * 128 + t] = 0.f;   // for next layer's L1
            int n0 = ch * 128 + q * 16;
            int nmax = NN - n0; if (nmax > 16) nmax = 16;
            float acc = 0.f;
            int curg = -1;
            #pragma unroll 4
            for (int i = 0; i < nmax; ++i) {
                int n = n0 + i;
                int g = batch[n];
                if (g != curg) {
                    if (curg >= 0) atomicAdd(&pl[(size_t)curg * DD + f], acc);
                    acc = 0.f; curg = g;
                }
                float v = bf2f(z2b[(size_t)n * DD + f]);
                v = fmaxf(fmaf(scv, v, shv), 0.f);
                hbuf[(size_t)n * DD + f] = f2bf_rne(v);
                acc += v;
            }
            if (curg >= 0) atomicAdd(&pl[(size_t)curg * DD + f], acc);
        }
        grid.sync();
    }

    // ================= readout =================
    int gc = bid * 512 + t;
    if (gc < GG * CC) {
        int g = gc / CC, c = gc - g * CC;
        float acc = 0.f;
        for (int l = 0; l < LL; ++l) {
            acc += bp[l * CC + c];
            const float* p  = pooled + ((size_t)l * GG + g) * DD;
            const float* wv = Wp + (size_t)l * DD * CC + c;
            #pragma unroll 8
            for (int ff = 0; ff < DD; ++ff) acc = fmaf(p[ff], wv[ff * CC], acc);
        }
        out[gc] = acc;
    }
}

extern "C" void kernel_launch(void* const* d_in, const int* in_sizes, int n_in,
                              void* d_out, int out_size, void* d_ws, size_t ws_size,
                              hipStream_t stream) {
    const float* x     = (const float*)d_in[0];
    const int*   ei    = (const int*)d_in[1];
    const int*   batch = (const int*)d_in[2];
    const float* eps   = (const float*)d_in[3];
    const float* W1    = (const float*)d_in[4];
    const float* b1    = (const float*)d_in[5];
    const float* g1    = (const float*)d_in[6];
    const float* be1   = (const float*)d_in[7];
    const float* W2    = (const float*)d_in[8];
    const float* b2    = (const float*)d_in[9];
    const float* gout  = (const float*)d_in[10];
    const float* beout = (const float*)d_in[11];
    const float* Wp    = (const float*)d_in[12];
    const float* bp    = (const float*)d_in[13];
    float* out = (float*)d_out;

    // ---- workspace layout (16B-aligned sections; bh+ctr adjacent to pooled
    //      so one memset covers bh+ctr+pooled+stats) ----
    unsigned int* stage = (unsigned int*)d_ws;          // EE*4
    int* adj   = (int*)(stage + EE);                    // EE*4
    int* offs  = adj + EE;                              // (NPAD+256)
    int* bo    = offs + NPAD + 256;                     // 400
    int* bcur  = bo + 400;                              // 400
    int* bh    = bcur + 400;                            // 400
    int* ctr   = bh + 400;                              // 16 phase counters
    float* pooled = (float*)(ctr + 16);                 // LL*GG*DD
    float* stats1 = pooled + (size_t)LL * GG * DD;      // SC*128
    float* stats2 = stats1 + SC * 128;                  // SC*128
    unsigned short* hb  = (unsigned short*)(stats2 + SC * 128);
    unsigned short* z1b = hb + N64;
    unsigned short* z2b = z1b + N64;
    unsigned short* wt  = z2b + N64;                    // 8*4096

    // ---- single memset: bh + ctr + pooled + stats1 + stats2 ----
    hipMemsetAsync(bh, 0, (400 + 16 + (size_t)LL * GG * DD + 2 * SC * 128) * sizeof(int), stream);
    // ---- fused prep (x->bf16 + pool0 | W^T | edge hist) ----
    prep_all_k<<<PREPG + 8 + 512, 256, 0, stream>>>(x, batch, hb, pooled, W1, W2, wt, ei, bh);
    bscan_k<<<1, 512, 0, stream>>>(bh, bo, bcur);
    partition_k<<<(EE + PCH - 1) / PCH, 256, 0, stream>>>(ei, bcur, stage);
    bucket_csr_k<<<NB, 256, 0, stream>>>(stage, bo, adj, offs);

    // ---- cooperative mega-kernel: all 4 layers + readout ----
    static int gridBlocks = 0;
    if (gridBlocks == 0) {
        int dev = 0; hipGetDevice(&dev);
        int cus = 256;
        hipDeviceGetAttribute(&cus, hipDeviceAttributeMultiprocessorCount, dev);
        int mpb = 1;
        hipOccupancyMaxActiveBlocksPerMultiprocessor(&mpb, gin_coop_k, 512, 0);
        if (mpb < 1) mpb = 1;
        gridBlocks = mpb * cus;
        if (gridBlocks > 1024) gridBlocks = 1024;
    }
    unsigned short* hbp = hb;
    void* cargs[] = {
        (void*)&hbp, (void*)&adj, (void*)&offs, (void*)&eps, (void*)&wt,
        (void*)&b1, (void*)&g1, (void*)&be1, (void*)&b2, (void*)&gout,
        (void*)&beout, (void*)&z1b, (void*)&z2b, (void*)&pooled,
        (void*)&stats1, (void*)&stats2, (void*)&batch, (void*)&ctr,
        (void*)&Wp, (void*)&bp, (void*)&out
    };
    hipLaunchCooperativeKernel((void*)gin_coop_k, dim3(gridBlocks), dim3(512),
                               cargs, 0, stream);
}

// Round 14
// 553.332 us; speedup vs baseline: 2.3927x; 1.7514x over previous
//
#include <hip/hip_runtime.h>

#define NN 100000
#define EE 1600000
#define DD 64
#define CC 10
#define GG 512
#define LL 5
#define NPAD 100352            // 392*256
#define N64 (NN * DD)
#define NB 392                 // coarse buckets (256 nodes each)
#define PCH 4096               // edges per partition block
#define BCAP 6144              // per-bucket LDS capacity (mean 4082, >30 sigma)
#define SC 8                   // BN stats shadow copies
#define PREPG 1563             // (NN+63)/64

typedef short bf16x8 __attribute__((ext_vector_type(8)));
typedef float f32x4  __attribute__((ext_vector_type(4)));
union U16 { uint4 u; bf16x8 h; };

__device__ __forceinline__ float bits2f(unsigned int b) { return __uint_as_float(b); }
__device__ __forceinline__ float bf2f(unsigned short s) { return __uint_as_float((unsigned int)s << 16); }
__device__ __forceinline__ unsigned short f2bf_rne(float v) {
    unsigned int b = __float_as_uint(v);
    return (unsigned short)((b + 0x7fffu + ((b >> 16) & 1u)) >> 16);
}
__device__ __forceinline__ void unpack8(uint4 u, float* f) {
    f[0] = bits2f(u.x << 16); f[1] = bits2f(u.x & 0xffff0000u);
    f[2] = bits2f(u.y << 16); f[3] = bits2f(u.y & 0xffff0000u);
    f[4] = bits2f(u.z << 16); f[5] = bits2f(u.z & 0xffff0000u);
    f[6] = bits2f(u.w << 16); f[7] = bits2f(u.w & 0xffff0000u);
}
__device__ __forceinline__ uint4 pack8(const float* f) {
    uint4 u;
    u.x = (unsigned int)f2bf_rne(f[0]) | ((unsigned int)f2bf_rne(f[1]) << 16);
    u.y = (unsigned int)f2bf_rne(f[2]) | ((unsigned int)f2bf_rne(f[3]) << 16);
    u.z = (unsigned int)f2bf_rne(f[4]) | ((unsigned int)f2bf_rne(f[5]) << 16);
    u.w = (unsigned int)f2bf_rne(f[6]) | ((unsigned int)f2bf_rne(f[7]) << 16);
    return u;
}
__device__ __forceinline__ void acc8(uint4 u, float* a) {
    float t[8];
    unpack8(u, t);
    #pragma unroll
    for (int k = 0; k < 8; ++k) a[k] += t[k];
}

// ======== fused prep: x->bf16 + layer-0 pool | W transpose | edge hist ========
__global__ __launch_bounds__(256) void prep_all_k(
    const float* __restrict__ x, const int* __restrict__ batch,
    unsigned short* __restrict__ hbuf, float* __restrict__ pooled,
    const float* __restrict__ W1, const float* __restrict__ W2,
    unsigned short* __restrict__ wt,
    const int* __restrict__ ei, int* __restrict__ bh)
{
    __shared__ int cnt[NB];
    const int bid = blockIdx.x;
    const int t = threadIdx.x;
    if (bid < PREPG) {
        int f = t & 63;
        int q = t >> 6;
        int n0 = bid * 64 + q * 16;
        int nmax = NN - n0; if (nmax > 16) nmax = 16;
        float acc = 0.f;
        int curg = -1;
        #pragma unroll 4
        for (int i = 0; i < nmax; ++i) {
            int n = n0 + i;
            int g = batch[n];
            if (g != curg) {
                if (curg >= 0) atomicAdd(&pooled[(size_t)curg * DD + f], acc);
                acc = 0.f; curg = g;
            }
            float v = x[(size_t)n * DD + f];
            hbuf[(size_t)n * DD + f] = f2bf_rne(v);
            acc += v;
        }
        if (curg >= 0) atomicAdd(&pooled[(size_t)curg * DD + f], acc);
    } else if (bid < PREPG + 8) {
        int mat = bid - PREPG;
        const float* src = (mat < 4) ? (W1 + (size_t)mat * 4096)
                                     : (W2 + (size_t)(mat - 4) * 4096);
        for (int idx = t; idx < 4096; idx += 256) {
            int c = idx >> 6, k = idx & 63;
            wt[(size_t)mat * 4096 + c * 64 + k] = f2bf_rne(src[k * 64 + c]);
        }
    } else {
        int hid = bid - PREPG - 8;          // 0..511
        for (int i = t; i < NB; i += 256) cnt[i] = 0;
        __syncthreads();
        for (int e = hid * 256 + t; e < EE; e += 512 * 256)
            atomicAdd(&cnt[ei[EE + e] >> 8], 1);
        __syncthreads();
        for (int i = t; i < NB; i += 256)
            if (cnt[i]) atomicAdd(&bh[i], cnt[i]);
    }
}

// ================= coarse scan =================
__global__ __launch_bounds__(512) void bscan_k(const int* __restrict__ bh,
                                               int* __restrict__ bo,
                                               int* __restrict__ bcur) {
    __shared__ int s[512];
    int t = threadIdx.x;
    int v = (t < NB) ? bh[t] : 0;
    s[t] = v;
    __syncthreads();
    for (int d = 1; d < 512; d <<= 1) {
        int a = (t >= d) ? s[t - d] : 0;
        __syncthreads();
        s[t] += a;
        __syncthreads();
    }
    int excl = s[t] - v;
    if (t < NB) { bo[t] = excl; bcur[t] = excl; }
    if (t == NB - 1) bo[NB] = excl + v;
}

// ============ partition edges into bucket-contiguous staging ============
// stage entry: src (bits 0..16) | dst-local-in-bucket (bits 17..24)
__global__ __launch_bounds__(256) void partition_k(const int* __restrict__ ei,
                                                   int* __restrict__ bcur,
                                                   unsigned int* __restrict__ stage) {
    __shared__ int hist[NB];
    __shared__ int base[NB];
    __shared__ int gbase[NB];
    __shared__ int cnt2[NB];
    __shared__ int scanbuf[512];
    __shared__ unsigned int pairs[PCH];
    __shared__ unsigned short pbkt[PCH];
    int t = threadIdx.x;
    int e0 = blockIdx.x * PCH;
    int nE = EE - e0; if (nE > PCH) nE = PCH;

    for (int i = t; i < NB; i += 256) { hist[i] = 0; cnt2[i] = 0; }
    __syncthreads();

    int mys[16], myd[16];
    #pragma unroll
    for (int i = 0; i < 16; ++i) {
        int idx = i * 256 + t;
        if (idx < nE) {
            mys[i] = ei[e0 + idx];
            myd[i] = ei[EE + e0 + idx];
            atomicAdd(&hist[myd[i] >> 8], 1);
        } else myd[i] = -1;
    }
    __syncthreads();

    scanbuf[t]       = (t < NB) ? hist[t] : 0;
    scanbuf[t + 256] = (t + 256 < NB) ? hist[t + 256] : 0;
    __syncthreads();
    for (int d = 1; d < 512; d <<= 1) {
        int a0 = (t >= d) ? scanbuf[t - d] : 0;
        int a1 = ((t + 256) >= d) ? scanbuf[t + 256 - d] : 0;
        __syncthreads();
        scanbuf[t] += a0;
        scanbuf[t + 256] += a1;
        __syncthreads();
    }
    if (t < NB)       base[t]       = scanbuf[t] - hist[t];
    if (t + 256 < NB) base[t + 256] = scanbuf[t + 256] - hist[t + 256];
    __syncthreads();

    #pragma unroll
    for (int i = 0; i < 16; ++i) {
        if (myd[i] >= 0) {
            int b = myd[i] >> 8;
            int p = base[b] + atomicAdd(&cnt2[b], 1);
            pairs[p] = (unsigned)mys[i] | ((unsigned)(myd[i] & 255) << 17);
            pbkt[p] = (unsigned short)b;
        }
    }
    __syncthreads();
    for (int i = t; i < NB; i += 256)
        if (hist[i]) gbase[i] = atomicAdd(&bcur[i], hist[i]);
    __syncthreads();
    for (int p = t; p < nE; p += 256) {
        int b = pbkt[p];
        stage[gbase[b] + (p - base[b])] = pairs[p];
    }
}

// ============ per-bucket CSR: adj + offs, all in LDS ============
__global__ __launch_bounds__(256) void bucket_csr_k(const unsigned int* __restrict__ stage,
                                                    const int* __restrict__ bo,
                                                    int* __restrict__ adj,
                                                    int* __restrict__ offs) {
    __shared__ int deg[256];
    __shared__ int sb[256];
    __shared__ int nb_[256];
    __shared__ int c2[256];
    __shared__ int loc[BCAP];
    int b = blockIdx.x;
    int s0 = bo[b], s1 = bo[b + 1];
    int cnt = s1 - s0;
    int t = threadIdx.x;

    deg[t] = 0;
    __syncthreads();
    for (int i = t; i < cnt; i += 256) atomicAdd(&deg[(stage[s0 + i] >> 17) & 255], 1);
    __syncthreads();
    sb[t] = deg[t];
    __syncthreads();
    for (int d = 1; d < 256; d <<= 1) {
        int a = (t >= d) ? sb[t - d] : 0;
        __syncthreads();
        sb[t] += a;
        __syncthreads();
    }
    int nbase = sb[t] - deg[t];
    nb_[t] = nbase;
    c2[t] = 0;
    offs[b * 256 + t] = s0 + nbase;
    __syncthreads();

    if (cnt <= BCAP) {
        for (int i = t; i < cnt; i += 256) {
            unsigned int pr = stage[s0 + i];
            int ln = (pr >> 17) & 255;
            int p = nb_[ln] + atomicAdd(&c2[ln], 1);
            loc[p] = (int)(pr & 0x1FFFF);
        }
        __syncthreads();
        for (int i = t; i < cnt; i += 256) adj[s0 + i] = loc[i];
    } else {            // statistically unreachable fallback
        for (int i = t; i < cnt; i += 256) {
            unsigned int pr = stage[s0 + i];
            int ln = (pr >> 17) & 255;
            int p = nb_[ln] + atomicAdd(&c2[ln], 1);
            adj[s0 + p] = (int)(pr & 0x1FFFF);
        }
    }
}

// ========== K1: R8 gather (verified 58us) -> LDS -> MFMA GEMM1 + stats1 ==========
__global__ __launch_bounds__(512, 8) void layer1_k(
    const unsigned short* __restrict__ hb, const int* __restrict__ adj,
    const int* __restrict__ offs, const float* __restrict__ epsArr, int l,
    const unsigned short* __restrict__ wtm, const float* __restrict__ bias,
    unsigned short* __restrict__ z1, float* __restrict__ stats1,
    float* __restrict__ stats2z)
{
    __shared__ unsigned short aLDS[64 * 64];   // 8KB, XOR-swizzled 16B units
    const int t = threadIdx.x;
    const int lane = t & 63;
    const int w = t >> 6;          // 0..7
    const int n15 = lane & 15;
    const int quad = lane >> 4;

    if (blockIdx.x < SC && t < 128) stats2z[blockIdx.x * 128 + t] = 0.f;

    const float epsv = 1.0f + epsArr[l];
    const int c8 = lane & 7;
    // ---- gather: one row per 8-lane group, adj software-pipelined ----
    {
        int lr = w * 8 + (lane >> 3);
        int n = blockIdx.x * 64 + lr;
        float acc[8] = {0.f,0.f,0.f,0.f,0.f,0.f,0.f,0.f};
        if (n < NN) {
            uint4 a = *(const uint4*)(hb + (size_t)n * DD + c8 * 8);
            unpack8(a, acc);
            #pragma unroll
            for (int j2 = 0; j2 < 8; ++j2) acc[j2] *= epsv;
            int j = offs[n], end = offs[n + 1];
            if (j < end) {
                int e1 = end - 1;
                int a0 = adj[j];
                int a1 = adj[(j + 1 < end) ? j + 1 : e1];
                int a2 = adj[(j + 2 < end) ? j + 2 : e1];
                int a3 = adj[(j + 3 < end) ? j + 3 : e1];
                #pragma unroll 1
                while (j < end) {
                    uint4 v0 = *(const uint4*)(hb + (size_t)a0 * DD + c8 * 8);
                    uint4 v1 = *(const uint4*)(hb + (size_t)a1 * DD + c8 * 8);
                    uint4 v2 = *(const uint4*)(hb + (size_t)a2 * DD + c8 * 8);
                    uint4 v3 = *(const uint4*)(hb + (size_t)a3 * DD + c8 * 8);
                    int jn = j + 4;
                    int b0 = adj[(jn     < end) ? jn     : e1];
                    int b1 = adj[(jn + 1 < end) ? jn + 1 : e1];
                    int b2 = adj[(jn + 2 < end) ? jn + 2 : e1];
                    int b3 = adj[(jn + 3 < end) ? jn + 3 : e1];
                    int rem = end - j;
                    acc8(v0, acc);
                    if (rem > 1) acc8(v1, acc);
                    if (rem > 2) acc8(v2, acc);
                    if (rem > 3) acc8(v3, acc);
                    a0 = b0; a1 = b1; a2 = b2; a3 = b3;
                    j = jn;
                }
            }
        }
        int pu = c8 ^ (lr & 7);
        *(uint4*)(aLDS + lr * 64 + pu * 8) = pack8(acc);
    }

    // ---- B fragments for this wave's 2 column tiles (issued before barrier) ----
    const int rt = w & 3;          // row tile (16 rows)
    const int cb = (w >> 2) * 2;   // first of 2 column tiles
    U16 bfr[2][2];
    #pragma unroll
    for (int ci = 0; ci < 2; ++ci)
        #pragma unroll
        for (int ks = 0; ks < 2; ++ks)
            bfr[ci][ks].u = *(const uint4*)(wtm + (size_t)((cb + ci) * 16 + n15) * 64 + ks * 32 + quad * 8);

    __syncthreads();               // A-rows in LDS are cross-wave

    // ---- A fragments from LDS (swizzled) ----
    U16 afr[2];
    int lr2 = rt * 16 + n15;
    #pragma unroll
    for (int ks = 0; ks < 2; ++ks) {
        int pu = (ks * 4 + quad) ^ (lr2 & 7);
        afr[ks].u = *(const uint4*)(aLDS + lr2 * 64 + pu * 8);
    }

    const int rowg0 = blockIdx.x * 64 + rt * 16;
    const int copy = blockIdx.x & (SC - 1);
    #pragma unroll
    for (int ci = 0; ci < 2; ++ci) {
        int ct = cb + ci;
        f32x4 acc = {0.f, 0.f, 0.f, 0.f};
        acc = __builtin_amdgcn_mfma_f32_16x16x32_bf16(afr[0].h, bfr[ci][0].h, acc, 0, 0, 0);
        acc = __builtin_amdgcn_mfma_f32_16x16x32_bf16(afr[1].h, bfr[ci][1].h, acc, 0, 0, 0);
        int col = ct * 16 + n15;
        float bcol = bias[col];
        float s = 0.f, ss = 0.f;
        #pragma unroll
        for (int r = 0; r < 4; ++r) {
            int rg = rowg0 + quad * 4 + r;
            float v = acc[r] + bcol;
            if (rg < NN) {
                z1[(size_t)rg * DD + col] = f2bf_rne(v);
                s += v;
                ss = fmaf(v, v, ss);
            }
        }
        s  += __shfl_xor(s, 16, 64);  s  += __shfl_xor(s, 32, 64);
        ss += __shfl_xor(ss, 16, 64); ss += __shfl_xor(ss, 32, 64);
        if (lane < 16) {
            atomicAdd(&stats1[copy * 128 + ct * 16 + lane], s);
            atomicAdd(&stats1[copy * 128 + 64 + ct * 16 + lane], ss);
        }
    }
}

// ========== K2 v2: inline BN1 + MFMA GEMM2 + stats2, 256 rows/block ==========
__global__ __launch_bounds__(256) void layer2_k(
    const unsigned short* __restrict__ z1, const float* __restrict__ stats1,
    const float* __restrict__ gamma, const float* __restrict__ beta, int off,
    const unsigned short* __restrict__ wtm, const float* __restrict__ bias,
    unsigned short* __restrict__ z2, float* __restrict__ stats2)
{
    __shared__ float ssS[128];
    const int t = threadIdx.x;
    const int lane = t & 63;
    const int w = t >> 6;
    const int n15 = lane & 15;
    const int quad = lane >> 4;
    const int base0 = blockIdx.x * 256;

    // ---- wt fragments once per block, issued before the stats barrier ----
    U16 bfr[4][2];
    #pragma unroll
    for (int ct = 0; ct < 4; ++ct)
        #pragma unroll
        for (int ks = 0; ks < 2; ++ks)
            bfr[ct][ks].u = *(const uint4*)(wtm + (size_t)(ct * 16 + n15) * 64 + ks * 32 + quad * 8);

    if (t < 64) {
        float S = 0.f, SS = 0.f;
        #pragma unroll
        for (int c = 0; c < SC; ++c) { S += stats1[c * 128 + t]; SS += stats1[c * 128 + 64 + t]; }
        float inv_n = 1.0f / (float)NN;
        float mean = S * inv_n;
        float var  = SS * inv_n - mean * mean;
        float sc = gamma[off + t] * rsqrtf(var + 1e-5f);
        ssS[t] = sc;
        ssS[64 + t] = beta[off + t] - sc * mean;
    }
    __syncthreads();

    float sacc[4]  = {0.f, 0.f, 0.f, 0.f};
    float ssacc[4] = {0.f, 0.f, 0.f, 0.f};
    #pragma unroll 1
    for (int ti = 0; ti < 4; ++ti) {
        const int rowg0 = base0 + ti * 64 + w * 16;
        int arow = rowg0 + n15;
        int arowc = (arow < NN) ? arow : (NN - 1);
        uint4 raw[2];
        #pragma unroll
        for (int ks = 0; ks < 2; ++ks)
            raw[ks] = *(const uint4*)(z1 + (size_t)arowc * DD + ks * 32 + quad * 8);

        U16 afr[2];
        #pragma unroll
        for (int ks = 0; ks < 2; ++ks) {
            float f[8];
            unpack8(raw[ks], f);
            int k0 = ks * 32 + quad * 8;
            #pragma unroll
            for (int j = 0; j < 8; ++j)
                f[j] = fmaxf(fmaf(ssS[k0 + j], f[j], ssS[64 + k0 + j]), 0.f);
            afr[ks].u = pack8(f);
        }

        #pragma unroll
        for (int ct = 0; ct < 4; ++ct) {
            f32x4 acc = {0.f, 0.f, 0.f, 0.f};
            acc = __builtin_amdgcn_mfma_f32_16x16x32_bf16(afr[0].h, bfr[ct][0].h, acc, 0, 0, 0);
            acc = __builtin_amdgcn_mfma_f32_16x16x32_bf16(afr[1].h, bfr[ct][1].h, acc, 0, 0, 0);
            int col = ct * 16 + n15;
            float bcol = bias[col];
            #pragma unroll
            for (int r = 0; r < 4; ++r) {
                int rg = rowg0 + quad * 4 + r;
                float v = acc[r] + bcol;
                if (rg < NN) {
                    z2[(size_t)rg * DD + col] = f2bf_rne(v);
                    sacc[ct] += v;
                    ssacc[ct] = fmaf(v, v, ssacc[ct]);
                }
            }
        }
    }
    const int copy = blockIdx.x & (SC - 1);
    #pragma unroll
    for (int ct = 0; ct < 4; ++ct) {
        float s = sacc[ct], ss = ssacc[ct];
        s  += __shfl_xor(s, 16, 64);  s  += __shfl_xor(s, 32, 64);
        ss += __shfl_xor(ss, 16, 64); ss += __shfl_xor(ss, 32, 64);
        if (lane < 16) {
            atomicAdd(&stats2[copy * 128 + ct * 16 + lane], s);
            atomicAdd(&stats2[copy * 128 + 64 + ct * 16 + lane], ss);
        }
    }
}

// ========== K3 v2: inline BN2 + ReLU + hb write + segmented pool, 256 rows/block ==========
__global__ __launch_bounds__(256) void layer3_k(
    const unsigned short* __restrict__ z2, const float* __restrict__ stats2,
    const float* __restrict__ gamma, const float* __restrict__ beta, int off,
    const int* __restrict__ batch, unsigned short* __restrict__ hout,
    float* __restrict__ pooled, float* __restrict__ stats1z)
{
    __shared__ float ssS[128];
    int t = threadIdx.x;
    if (blockIdx.x < SC && t < 128) stats1z[blockIdx.x * 128 + t] = 0.f;
    if (t < 64) {
        float S = 0.f, SS = 0.f;
        #pragma unroll
        for (int c = 0; c < SC; ++c) { S += stats2[c * 128 + t]; SS += stats2[c * 128 + 64 + t]; }
        float inv_n = 1.0f / (float)NN;
        float mean = S * inv_n;
        float var  = SS * inv_n - mean * mean;
        float sc = gamma[off + t] * rsqrtf(var + 1e-5f);
        ssS[t] = sc;
        ssS[64 + t] = beta[off + t] - sc * mean;
    }
    __syncthreads();

    int f = t & 63;
    int q = t >> 6;
    float sc = ssS[f], sh = ssS[64 + f];
    #pragma unroll 1
    for (int ti = 0; ti < 4; ++ti) {
        int n0 = blockIdx.x * 256 + ti * 64 + q * 16;
        int nmax = NN - n0; if (nmax > 16) nmax = 16;
        float acc = 0.f;
        int curg = -1;
        #pragma unroll 4
        for (int i = 0; i < nmax; ++i) {
            int n = n0 + i;
            int g = batch[n];
            if (g != curg) {
                if (curg >= 0) atomicAdd(&pooled[(size_t)curg * DD + f], acc);
                acc = 0.f; curg = g;
            }
            float v = bf2f(z2[(size_t)n * DD + f]);
            v = fmaxf(fmaf(sc, v, sh), 0.f);
            hout[(size_t)n * DD + f] = f2bf_rne(v);
            acc += v;
        }
        if (curg >= 0) atomicAdd(&pooled[(size_t)curg * DD + f], acc);
    }
}

// ================= jumping-knowledge readout =================
__global__ void readout_k(const float* __restrict__ pooled,
                          const float* __restrict__ Wp, const float* __restrict__ bp,
                          float* __restrict__ out)
{
    int gc = blockIdx.x * blockDim.x + threadIdx.x;
    if (gc >= GG * CC) return;
    int g = gc / CC, c = gc - g * CC;
    float acc = 0.f;
    for (int l = 0; l < LL; ++l) {
        acc += bp[l * CC + c];
        const float* p  = pooled + ((size_t)l * GG + g) * DD;
        const float* wv = Wp + (size_t)l * DD * CC + c;
        #pragma unroll 8
        for (int f = 0; f < DD; ++f) acc = fmaf(p[f], wv[f * CC], acc);
    }
    out[gc] = acc;
}

extern "C" void kernel_launch(void* const* d_in, const int* in_sizes, int n_in,
                              void* d_out, int out_size, void* d_ws, size_t ws_size,
                              hipStream_t stream) {
    const float* x     = (const float*)d_in[0];
    const int*   ei    = (const int*)d_in[1];
    const int*   batch = (const int*)d_in[2];
    const float* eps   = (const float*)d_in[3];
    const float* W1    = (const float*)d_in[4];
    const float* b1    = (const float*)d_in[5];
    const float* g1    = (const float*)d_in[6];
    const float* be1   = (const float*)d_in[7];
    const float* W2    = (const float*)d_in[8];
    const float* b2    = (const float*)d_in[9];
    const float* gout  = (const float*)d_in[10];
    const float* beout = (const float*)d_in[11];
    const float* Wp    = (const float*)d_in[12];
    const float* bp    = (const float*)d_in[13];
    float* out = (float*)d_out;

    // ---- workspace layout (16B-aligned sections; bh adjacent to pooled so
    //      one memset covers bh+pooled+stats) ----
    unsigned int* stage = (unsigned int*)d_ws;          // EE*4
    int* adj   = (int*)(stage + EE);                    // EE*4
    int* offs  = adj + EE;                              // (NPAD+256)
    int* bo    = offs + NPAD + 256;                     // 400
    int* bcur  = bo + 400;                              // 400
    int* bh    = bcur + 400;                            // 400
    float* pooled = (float*)(bh + 400);                 // LL*GG*DD
    float* stats1 = pooled + (size_t)LL * GG * DD;      // SC*128
    float* stats2 = stats1 + SC * 128;                  // SC*128
    unsigned short* hb  = (unsigned short*)(stats2 + SC * 128);
    unsigned short* z1b = hb + N64;
    unsigned short* z2b = z1b + N64;
    unsigned short* wt  = z2b + N64;                    // 8*4096

    // ---- single memset: bh + pooled + stats1 + stats2 ----
    hipMemsetAsync(bh, 0, (400 + (size_t)LL * GG * DD + 2 * SC * 128) * sizeof(int), stream);
    // ---- fused prep (x->bf16 + pool0 | W^T | edge hist) ----
    prep_all_k<<<PREPG + 8 + 512, 256, 0, stream>>>(x, batch, hb, pooled, W1, W2, wt, ei, bh);
    bscan_k<<<1, 512, 0, stream>>>(bh, bo, bcur);
    partition_k<<<(EE + PCH - 1) / PCH, 256, 0, stream>>>(ei, bcur, stage);
    bucket_csr_k<<<NB, 256, 0, stream>>>(stage, bo, adj, offs);

    const int gemm_grid = (NN + 63) / 64;       // layer1: 64 rows/block
    const int big_grid  = (NN + 255) / 256;     // layer2/3: 256 rows/block
    for (int l = 0; l < LL - 1; ++l) {
        layer1_k<<<gemm_grid, 512, 0, stream>>>(
            hb, adj, offs, eps, l, wt + (size_t)l * 4096, b1 + l * DD, z1b, stats1, stats2);
        layer2_k<<<big_grid, 256, 0, stream>>>(
            z1b, stats1, g1, be1, l * DD, wt + (size_t)(4 + l) * 4096, b2 + l * DD, z2b, stats2);
        layer3_k<<<big_grid, 256, 0, stream>>>(
            z2b, stats2, gout, beout, l * DD, batch, hb,
            pooled + (size_t)(l + 1) * GG * DD, stats1);
    }
    readout_k<<<(GG * CC + 255) / 256, 256, 0, stream>>>(pooled, Wp, bp, out);
}

// Round 15
// 550.217 us; speedup vs baseline: 2.4062x; 1.0057x over previous
//
#include <hip/hip_runtime.h>

#define NN 100000
#define EE 1600000
#define DD 64
#define CC 10
#define GG 512
#define LL 5
#define NPAD 100352            // 392*256
#define N64 (NN * DD)
#define NB 392                 // coarse buckets (256 nodes each)
#define PCH 4096               // edges per partition block
#define BCAP 6144              // per-bucket LDS capacity (mean 4082, >30 sigma)
#define SC 8                   // BN stats shadow copies
#define PREPG 1563             // (NN+63)/64

typedef short bf16x8 __attribute__((ext_vector_type(8)));
typedef float f32x4  __attribute__((ext_vector_type(4)));
union U16 { uint4 u; bf16x8 h; };

__device__ __forceinline__ float bits2f(unsigned int b) { return __uint_as_float(b); }
__device__ __forceinline__ float bf2f(unsigned short s) { return __uint_as_float((unsigned int)s << 16); }
__device__ __forceinline__ unsigned short f2bf_rne(float v) {
    unsigned int b = __float_as_uint(v);
    return (unsigned short)((b + 0x7fffu + ((b >> 16) & 1u)) >> 16);
}
__device__ __forceinline__ void unpack8(uint4 u, float* f) {
    f[0] = bits2f(u.x << 16); f[1] = bits2f(u.x & 0xffff0000u);
    f[2] = bits2f(u.y << 16); f[3] = bits2f(u.y & 0xffff0000u);
    f[4] = bits2f(u.z << 16); f[5] = bits2f(u.z & 0xffff0000u);
    f[6] = bits2f(u.w << 16); f[7] = bits2f(u.w & 0xffff0000u);
}
__device__ __forceinline__ uint4 pack8(const float* f) {
    uint4 u;
    u.x = (unsigned int)f2bf_rne(f[0]) | ((unsigned int)f2bf_rne(f[1]) << 16);
    u.y = (unsigned int)f2bf_rne(f[2]) | ((unsigned int)f2bf_rne(f[3]) << 16);
    u.z = (unsigned int)f2bf_rne(f[4]) | ((unsigned int)f2bf_rne(f[5]) << 16);
    u.w = (unsigned int)f2bf_rne(f[6]) | ((unsigned int)f2bf_rne(f[7]) << 16);
    return u;
}
__device__ __forceinline__ void acc8(uint4 u, float* a) {
    float t[8];
    unpack8(u, t);
    #pragma unroll
    for (int k = 0; k < 8; ++k) a[k] += t[k];
}

// ======== fused prep: x->bf16 + layer-0 pool | W transpose | edge hist ========
__global__ __launch_bounds__(256) void prep_all_k(
    const float* __restrict__ x, const int* __restrict__ batch,
    unsigned short* __restrict__ hbuf, float* __restrict__ pooled,
    const float* __restrict__ W1, const float* __restrict__ W2,
    unsigned short* __restrict__ wt,
    const int* __restrict__ ei, int* __restrict__ bh)
{
    __shared__ int cnt[NB];
    const int bid = blockIdx.x;
    const int t = threadIdx.x;
    if (bid < PREPG) {
        int f = t & 63;
        int q = t >> 6;
        int n0 = bid * 64 + q * 16;
        int nmax = NN - n0; if (nmax > 16) nmax = 16;
        float acc = 0.f;
        int curg = -1;
        #pragma unroll 4
        for (int i = 0; i < nmax; ++i) {
            int n = n0 + i;
            int g = batch[n];
            if (g != curg) {
                if (curg >= 0) atomicAdd(&pooled[(size_t)curg * DD + f], acc);
                acc = 0.f; curg = g;
            }
            float v = x[(size_t)n * DD + f];
            hbuf[(size_t)n * DD + f] = f2bf_rne(v);
            acc += v;
        }
        if (curg >= 0) atomicAdd(&pooled[(size_t)curg * DD + f], acc);
    } else if (bid < PREPG + 8) {
        int mat = bid - PREPG;
        const float* src = (mat < 4) ? (W1 + (size_t)mat * 4096)
                                     : (W2 + (size_t)(mat - 4) * 4096);
        for (int idx = t; idx < 4096; idx += 256) {
            int c = idx >> 6, k = idx & 63;
            wt[(size_t)mat * 4096 + c * 64 + k] = f2bf_rne(src[k * 64 + c]);
        }
    } else {
        int hid = bid - PREPG - 8;          // 0..511
        for (int i = t; i < NB; i += 256) cnt[i] = 0;
        __syncthreads();
        for (int e = hid * 256 + t; e < EE; e += 512 * 256)
            atomicAdd(&cnt[ei[EE + e] >> 8], 1);
        __syncthreads();
        for (int i = t; i < NB; i += 256)
            if (cnt[i]) atomicAdd(&bh[i], cnt[i]);
    }
}

// ================= coarse scan =================
__global__ __launch_bounds__(512) void bscan_k(const int* __restrict__ bh,
                                               int* __restrict__ bo,
                                               int* __restrict__ bcur) {
    __shared__ int s[512];
    int t = threadIdx.x;
    int v = (t < NB) ? bh[t] : 0;
    s[t] = v;
    __syncthreads();
    for (int d = 1; d < 512; d <<= 1) {
        int a = (t >= d) ? s[t - d] : 0;
        __syncthreads();
        s[t] += a;
        __syncthreads();
    }
    int excl = s[t] - v;
    if (t < NB) { bo[t] = excl; bcur[t] = excl; }
    if (t == NB - 1) bo[NB] = excl + v;
}

// ============ partition edges into bucket-contiguous staging ============
// stage entry: src (bits 0..16) | dst-local-in-bucket (bits 17..24)
__global__ __launch_bounds__(256) void partition_k(const int* __restrict__ ei,
                                                   int* __restrict__ bcur,
                                                   unsigned int* __restrict__ stage) {
    __shared__ int hist[NB];
    __shared__ int base[NB];
    __shared__ int gbase[NB];
    __shared__ int cnt2[NB];
    __shared__ int scanbuf[512];
    __shared__ unsigned int pairs[PCH];
    __shared__ unsigned short pbkt[PCH];
    int t = threadIdx.x;
    int e0 = blockIdx.x * PCH;
    int nE = EE - e0; if (nE > PCH) nE = PCH;

    for (int i = t; i < NB; i += 256) { hist[i] = 0; cnt2[i] = 0; }
    __syncthreads();

    int mys[16], myd[16];
    #pragma unroll
    for (int i = 0; i < 16; ++i) {
        int idx = i * 256 + t;
        if (idx < nE) {
            mys[i] = ei[e0 + idx];
            myd[i] = ei[EE + e0 + idx];
            atomicAdd(&hist[myd[i] >> 8], 1);
        } else myd[i] = -1;
    }
    __syncthreads();

    scanbuf[t]       = (t < NB) ? hist[t] : 0;
    scanbuf[t + 256] = (t + 256 < NB) ? hist[t + 256] : 0;
    __syncthreads();
    for (int d = 1; d < 512; d <<= 1) {
        int a0 = (t >= d) ? scanbuf[t - d] : 0;
        int a1 = ((t + 256) >= d) ? scanbuf[t + 256 - d] : 0;
        __syncthreads();
        scanbuf[t] += a0;
        scanbuf[t + 256] += a1;
        __syncthreads();
    }
    if (t < NB)       base[t]       = scanbuf[t] - hist[t];
    if (t + 256 < NB) base[t + 256] = scanbuf[t + 256] - hist[t + 256];
    __syncthreads();

    #pragma unroll
    for (int i = 0; i < 16; ++i) {
        if (myd[i] >= 0) {
            int b = myd[i] >> 8;
            int p = base[b] + atomicAdd(&cnt2[b], 1);
            pairs[p] = (unsigned)mys[i] | ((unsigned)(myd[i] & 255) << 17);
            pbkt[p] = (unsigned short)b;
        }
    }
    __syncthreads();
    for (int i = t; i < NB; i += 256)
        if (hist[i]) gbase[i] = atomicAdd(&bcur[i], hist[i]);
    __syncthreads();
    for (int p = t; p < nE; p += 256) {
        int b = pbkt[p];
        stage[gbase[b] + (p - base[b])] = pairs[p];
    }
}

// ============ per-bucket CSR: adj + offs, all in LDS ============
__global__ __launch_bounds__(256) void bucket_csr_k(const unsigned int* __restrict__ stage,
                                                    const int* __restrict__ bo,
                                                    int* __restrict__ adj,
                                                    int* __restrict__ offs) {
    __shared__ int deg[256];
    __shared__ int sb[256];
    __shared__ int nb_[256];
    __shared__ int c2[256];
    __shared__ int loc[BCAP];
    int b = blockIdx.x;
    int s0 = bo[b], s1 = bo[b + 1];
    int cnt = s1 - s0;
    int t = threadIdx.x;

    deg[t] = 0;
    __syncthreads();
    for (int i = t; i < cnt; i += 256) atomicAdd(&deg[(stage[s0 + i] >> 17) & 255], 1);
    __syncthreads();
    sb[t] = deg[t];
    __syncthreads();
    for (int d = 1; d < 256; d <<= 1) {
        int a = (t >= d) ? sb[t - d] : 0;
        __syncthreads();
        sb[t] += a;
        __syncthreads();
    }
    int nbase = sb[t] - deg[t];
    nb_[t] = nbase;
    c2[t] = 0;
    offs[b * 256 + t] = s0 + nbase;
    __syncthreads();

    if (cnt <= BCAP) {
        for (int i = t; i < cnt; i += 256) {
            unsigned int pr = stage[s0 + i];
            int ln = (pr >> 17) & 255;
            int p = nb_[ln] + atomicAdd(&c2[ln], 1);
            loc[p] = (int)(pr & 0x1FFFF);
        }
        __syncthreads();
        for (int i = t; i < cnt; i += 256) adj[s0 + i] = loc[i];
    } else {            // statistically unreachable fallback
        for (int i = t; i < cnt; i += 256) {
            unsigned int pr = stage[s0 + i];
            int ln = (pr >> 17) & 255;
            int p = nb_[ln] + atomicAdd(&c2[ln], 1);
            adj[s0 + p] = (int)(pr & 0x1FFFF);
        }
    }
}

// ========== K1 v10: double-buffered hb-load pipeline -> LDS -> MFMA GEMM1 + stats1 ==========
// R14 analysis: VGPR=24 forces consume-as-returned (4 uint4 dests alone need
// 16 regs) -> effective depth 1-2 -> Little's law caps scattered BW at the
// observed 3.1 TB/s. v10 pipelines the HB LOADS one batch ahead through NAMED
// uint4 regs (cv/nv), with sched_barrier(0) pinning loads above the VALU
// (rule 18: hipcc hoists past inline waits otherwise). Compiler then emits a
// counted vmcnt(8) -- 8 vmem ops stay in flight across each accumulate.
// launch_bounds(512,6): VGPR cap ~85 so the ~64-reg pipeline CANNOT spill
// (R2/R12 lesson); 6 waves/EU = R1's proven occupancy. Clamped tail indices
// + predicated acc8 -> edge order preserved -> bit-identical numerics.
__global__ __launch_bounds__(512, 6) void layer1_k(
    const unsigned short* __restrict__ hb, const int* __restrict__ adj,
    const int* __restrict__ offs, const float* __restrict__ epsArr, int l,
    const unsigned short* __restrict__ wtm, const float* __restrict__ bias,
    unsigned short* __restrict__ z1, float* __restrict__ stats1,
    float* __restrict__ stats2z)
{
    __shared__ unsigned short aLDS[64 * 64];   // 8KB, XOR-swizzled 16B units
    const int t = threadIdx.x;
    const int lane = t & 63;
    const int w = t >> 6;          // 0..7
    const int n15 = lane & 15;
    const int quad = lane >> 4;

    if (blockIdx.x < SC && t < 128) stats2z[blockIdx.x * 128 + t] = 0.f;

    const float epsv = 1.0f + epsArr[l];
    const int c8 = lane & 7;
    // ---- gather: one row per 8-lane group; hb loads double-buffered ----
    {
        int lr = w * 8 + (lane >> 3);
        int n = blockIdx.x * 64 + lr;
        float acc[8] = {0.f,0.f,0.f,0.f,0.f,0.f,0.f,0.f};
        if (n < NN) {
            uint4 a = *(const uint4*)(hb + (size_t)n * DD + c8 * 8);
            unpack8(a, acc);
            #pragma unroll
            for (int j2 = 0; j2 < 8; ++j2) acc[j2] *= epsv;
            int j = offs[n], end = offs[n + 1];
            if (j < end) {
                int e1 = end - 1;
                // prologue: adj batches A (iter j) and B (iter j+4)
                int a0 = adj[j];
                int a1 = adj[(j + 1 < end) ? j + 1 : e1];
                int a2 = adj[(j + 2 < end) ? j + 2 : e1];
                int a3 = adj[(j + 3 < end) ? j + 3 : e1];
                int b0 = adj[(j + 4 < end) ? j + 4 : e1];
                int b1 = adj[(j + 5 < end) ? j + 5 : e1];
                int b2 = adj[(j + 6 < end) ? j + 6 : e1];
                int b3 = adj[(j + 7 < end) ? j + 7 : e1];
                // current hb batch
                uint4 cv0 = *(const uint4*)(hb + (size_t)a0 * DD + c8 * 8);
                uint4 cv1 = *(const uint4*)(hb + (size_t)a1 * DD + c8 * 8);
                uint4 cv2 = *(const uint4*)(hb + (size_t)a2 * DD + c8 * 8);
                uint4 cv3 = *(const uint4*)(hb + (size_t)a3 * DD + c8 * 8);
                #pragma unroll 1
                while (j < end) {
                    // issue NEXT hb batch (b indices, clamped -> always valid)
                    uint4 nv0 = *(const uint4*)(hb + (size_t)b0 * DD + c8 * 8);
                    uint4 nv1 = *(const uint4*)(hb + (size_t)b1 * DD + c8 * 8);
                    uint4 nv2 = *(const uint4*)(hb + (size_t)b2 * DD + c8 * 8);
                    uint4 nv3 = *(const uint4*)(hb + (size_t)b3 * DD + c8 * 8);
                    // adj batch C (iter j+8)
                    int jn2 = j + 8;
                    int c0 = adj[(jn2     < end) ? jn2     : e1];
                    int c1 = adj[(jn2 + 1 < end) ? jn2 + 1 : e1];
                    int c2 = adj[(jn2 + 2 < end) ? jn2 + 2 : e1];
                    int c3 = adj[(jn2 + 3 < end) ? jn2 + 3 : e1];
                    // pin: all loads above issue before the VALU below
                    __builtin_amdgcn_sched_barrier(0);
                    // accumulate current batch (waits vmcnt(8): nv+adjC in flight)
                    int rem = end - j;
                    acc8(cv0, acc);
                    if (rem > 1) acc8(cv1, acc);
                    if (rem > 2) acc8(cv2, acc);
                    if (rem > 3) acc8(cv3, acc);
                    cv0 = nv0; cv1 = nv1; cv2 = nv2; cv3 = nv3;
                    b0 = c0; b1 = c1; b2 = c2; b3 = c3;
                    j += 4;
                }
            }
        }
        int pu = c8 ^ (lr & 7);
        *(uint4*)(aLDS + lr * 64 + pu * 8) = pack8(acc);
    }

    // ---- B fragments for this wave's 2 column tiles (issued before barrier) ----
    const int rt = w & 3;          // row tile (16 rows)
    const int cb = (w >> 2) * 2;   // first of 2 column tiles
    U16 bfr[2][2];
    #pragma unroll
    for (int ci = 0; ci < 2; ++ci)
        #pragma unroll
        for (int ks = 0; ks < 2; ++ks)
            bfr[ci][ks].u = *(const uint4*)(wtm + (size_t)((cb + ci) * 16 + n15) * 64 + ks * 32 + quad * 8);

    __syncthreads();               // A-rows in LDS are cross-wave

    // ---- A fragments from LDS (swizzled) ----
    U16 afr[2];
    int lr2 = rt * 16 + n15;
    #pragma unroll
    for (int ks = 0; ks < 2; ++ks) {
        int pu = (ks * 4 + quad) ^ (lr2 & 7);
        afr[ks].u = *(const uint4*)(aLDS + lr2 * 64 + pu * 8);
    }

    const int rowg0 = blockIdx.x * 64 + rt * 16;
    const int copy = blockIdx.x & (SC - 1);
    #pragma unroll
    for (int ci = 0; ci < 2; ++ci) {
        int ct = cb + ci;
        f32x4 acc = {0.f, 0.f, 0.f, 0.f};
        acc = __builtin_amdgcn_mfma_f32_16x16x32_bf16(afr[0].h, bfr[ci][0].h, acc, 0, 0, 0);
        acc = __builtin_amdgcn_mfma_f32_16x16x32_bf16(afr[1].h, bfr[ci][1].h, acc, 0, 0, 0);
        int col = ct * 16 + n15;
        float bcol = bias[col];
        float s = 0.f, ss = 0.f;
        #pragma unroll
        for (int r = 0; r < 4; ++r) {
            int rg = rowg0 + quad * 4 + r;
            float v = acc[r] + bcol;
            if (rg < NN) {
                z1[(size_t)rg * DD + col] = f2bf_rne(v);
                s += v;
                ss = fmaf(v, v, ss);
            }
        }
        s  += __shfl_xor(s, 16, 64);  s  += __shfl_xor(s, 32, 64);
        ss += __shfl_xor(ss, 16, 64); ss += __shfl_xor(ss, 32, 64);
        if (lane < 16) {
            atomicAdd(&stats1[copy * 128 + ct * 16 + lane], s);
            atomicAdd(&stats1[copy * 128 + 64 + ct * 16 + lane], ss);
        }
    }
}

// ========== K2 v2: inline BN1 + MFMA GEMM2 + stats2, 256 rows/block ==========
__global__ __launch_bounds__(256) void layer2_k(
    const unsigned short* __restrict__ z1, const float* __restrict__ stats1,
    const float* __restrict__ gamma, const float* __restrict__ beta, int off,
    const unsigned short* __restrict__ wtm, const float* __restrict__ bias,
    unsigned short* __restrict__ z2, float* __restrict__ stats2)
{
    __shared__ float ssS[128];
    const int t = threadIdx.x;
    const int lane = t & 63;
    const int w = t >> 6;
    const int n15 = lane & 15;
    const int quad = lane >> 4;
    const int base0 = blockIdx.x * 256;

    // ---- wt fragments once per block, issued before the stats barrier ----
    U16 bfr[4][2];
    #pragma unroll
    for (int ct = 0; ct < 4; ++ct)
        #pragma unroll
        for (int ks = 0; ks < 2; ++ks)
            bfr[ct][ks].u = *(const uint4*)(wtm + (size_t)(ct * 16 + n15) * 64 + ks * 32 + quad * 8);

    if (t < 64) {
        float S = 0.f, SS = 0.f;
        #pragma unroll
        for (int c = 0; c < SC; ++c) { S += stats1[c * 128 + t]; SS += stats1[c * 128 + 64 + t]; }
        float inv_n = 1.0f / (float)NN;
        float mean = S * inv_n;
        float var  = SS * inv_n - mean * mean;
        float sc = gamma[off + t] * rsqrtf(var + 1e-5f);
        ssS[t] = sc;
        ssS[64 + t] = beta[off + t] - sc * mean;
    }
    __syncthreads();

    float sacc[4]  = {0.f, 0.f, 0.f, 0.f};
    float ssacc[4] = {0.f, 0.f, 0.f, 0.f};
    #pragma unroll 1
    for (int ti = 0; ti < 4; ++ti) {
        const int rowg0 = base0 + ti * 64 + w * 16;
        int arow = rowg0 + n15;
        int arowc = (arow < NN) ? arow : (NN - 1);
        uint4 raw[2];
        #pragma unroll
        for (int ks = 0; ks < 2; ++ks)
            raw[ks] = *(const uint4*)(z1 + (size_t)arowc * DD + ks * 32 + quad * 8);

        U16 afr[2];
        #pragma unroll
        for (int ks = 0; ks < 2; ++ks) {
            float f[8];
            unpack8(raw[ks], f);
            int k0 = ks * 32 + quad * 8;
            #pragma unroll
            for (int j = 0; j < 8; ++j)
                f[j] = fmaxf(fmaf(ssS[k0 + j], f[j], ssS[64 + k0 + j]), 0.f);
            afr[ks].u = pack8(f);
        }

        #pragma unroll
        for (int ct = 0; ct < 4; ++ct) {
            f32x4 acc = {0.f, 0.f, 0.f, 0.f};
            acc = __builtin_amdgcn_mfma_f32_16x16x32_bf16(afr[0].h, bfr[ct][0].h, acc, 0, 0, 0);
            acc = __builtin_amdgcn_mfma_f32_16x16x32_bf16(afr[1].h, bfr[ct][1].h, acc, 0, 0, 0);
            int col = ct * 16 + n15;
            float bcol = bias[col];
            #pragma unroll
            for (int r = 0; r < 4; ++r) {
                int rg = rowg0 + quad * 4 + r;
                float v = acc[r] + bcol;
                if (rg < NN) {
                    z2[(size_t)rg * DD + col] = f2bf_rne(v);
                    sacc[ct] += v;
                    ssacc[ct] = fmaf(v, v, ssacc[ct]);
                }
            }
        }
    }
    const int copy = blockIdx.x & (SC - 1);
    #pragma unroll
    for (int ct = 0; ct < 4; ++ct) {
        float s = sacc[ct], ss = ssacc[ct];
        s  += __shfl_xor(s, 16, 64);  s  += __shfl_xor(s, 32, 64);
        ss += __shfl_xor(ss, 16, 64); ss += __shfl_xor(ss, 32, 64);
        if (lane < 16) {
            atomicAdd(&stats2[copy * 128 + ct * 16 + lane], s);
            atomicAdd(&stats2[copy * 128 + 64 + ct * 16 + lane], ss);
        }
    }
}

// ========== K3 v2: inline BN2 + ReLU + hb write + segmented pool, 256 rows/block ==========
__global__ __launch_bounds__(256) void layer3_k(
    const unsigned short* __restrict__ z2, const float* __restrict__ stats2,
    const float* __restrict__ gamma, const float* __restrict__ beta, int off,
    const int* __restrict__ batch, unsigned short* __restrict__ hout,
    float* __restrict__ pooled, float* __restrict__ stats1z)
{
    __shared__ float ssS[128];
    int t = threadIdx.x;
    if (blockIdx.x < SC && t < 128) stats1z[blockIdx.x * 128 + t] = 0.f;
    if (t < 64) {
        float S = 0.f, SS = 0.f;
        #pragma unroll
        for (int c = 0; c < SC; ++c) { S += stats2[c * 128 + t]; SS += stats2[c * 128 + 64 + t]; }
        float inv_n = 1.0f / (float)NN;
        float mean = S * inv_n;
        float var  = SS * inv_n - mean * mean;
        float sc = gamma[off + t] * rsqrtf(var + 1e-5f);
        ssS[t] = sc;
        ssS[64 + t] = beta[off + t] - sc * mean;
    }
    __syncthreads();

    int f = t & 63;
    int q = t >> 6;
    float sc = ssS[f], sh = ssS[64 + f];
    #pragma unroll 1
    for (int ti = 0; ti < 4; ++ti) {
        int n0 = blockIdx.x * 256 + ti * 64 + q * 16;
        int nmax = NN - n0; if (nmax > 16) nmax = 16;
        float acc = 0.f;
        int curg = -1;
        #pragma unroll 4
        for (int i = 0; i < nmax; ++i) {
            int n = n0 + i;
            int g = batch[n];
            if (g != curg) {
                if (curg >= 0) atomicAdd(&pooled[(size_t)curg * DD + f], acc);
                acc = 0.f; curg = g;
            }
            float v = bf2f(z2[(size_t)n * DD + f]);
            v = fmaxf(fmaf(sc, v, sh), 0.f);
            hout[(size_t)n * DD + f] = f2bf_rne(v);
            acc += v;
        }
        if (curg >= 0) atomicAdd(&pooled[(size_t)curg * DD + f], acc);
    }
}

// ================= jumping-knowledge readout =================
__global__ void readout_k(const float* __restrict__ pooled,
                          const float* __restrict__ Wp, const float* __restrict__ bp,
                          float* __restrict__ out)
{
    int gc = blockIdx.x * blockDim.x + threadIdx.x;
    if (gc >= GG * CC) return;
    int g = gc / CC, c = gc - g * CC;
    float acc = 0.f;
    for (int l = 0; l < LL; ++l) {
        acc += bp[l * CC + c];
        const float* p  = pooled + ((size_t)l * GG + g) * DD;
        const float* wv = Wp + (size_t)l * DD * CC + c;
        #pragma unroll 8
        for (int f = 0; f < DD; ++f) acc = fmaf(p[f], wv[f * CC], acc);
    }
    out[gc] = acc;
}

extern "C" void kernel_launch(void* const* d_in, const int* in_sizes, int n_in,
                              void* d_out, int out_size, void* d_ws, size_t ws_size,
                              hipStream_t stream) {
    const float* x     = (const float*)d_in[0];
    const int*   ei    = (const int*)d_in[1];
    const int*   batch = (const int*)d_in[2];
    const float* eps   = (const float*)d_in[3];
    const float* W1    = (const float*)d_in[4];
    const float* b1    = (const float*)d_in[5];
    const float* g1    = (const float*)d_in[6];
    const float* be1   = (const float*)d_in[7];
    const float* W2    = (const float*)d_in[8];
    const float* b2    = (const float*)d_in[9];
    const float* gout  = (const float*)d_in[10];
    const float* beout = (const float*)d_in[11];
    const float* Wp    = (const float*)d_in[12];
    const float* bp    = (const float*)d_in[13];
    float* out = (float*)d_out;

    // ---- workspace layout (16B-aligned sections; bh adjacent to pooled so
    //      one memset covers bh+pooled+stats) ----
    unsigned int* stage = (unsigned int*)d_ws;          // EE*4
    int* adj   = (int*)(stage + EE);                    // EE*4
    int* offs  = adj + EE;                              // (NPAD+256)
    int* bo    = offs + NPAD + 256;                     // 400
    int* bcur  = bo + 400;                              // 400
    int* bh    = bcur + 400;                            // 400
    float* pooled = (float*)(bh + 400);                 // LL*GG*DD
    float* stats1 = pooled + (size_t)LL * GG * DD;      // SC*128
    float* stats2 = stats1 + SC * 128;                  // SC*128
    unsigned short* hb  = (unsigned short*)(stats2 + SC * 128);
    unsigned short* z1b = hb + N64;
    unsigned short* z2b = z1b + N64;
    unsigned short* wt  = z2b + N64;                    // 8*4096

    // ---- single memset: bh + pooled + stats1 + stats2 ----
    hipMemsetAsync(bh, 0, (400 + (size_t)LL * GG * DD + 2 * SC * 128) * sizeof(int), stream);
    // ---- fused prep (x->bf16 + pool0 | W^T | edge hist) ----
    prep_all_k<<<PREPG + 8 + 512, 256, 0, stream>>>(x, batch, hb, pooled, W1, W2, wt, ei, bh);
    bscan_k<<<1, 512, 0, stream>>>(bh, bo, bcur);
    partition_k<<<(EE + PCH - 1) / PCH, 256, 0, stream>>>(ei, bcur, stage);
    bucket_csr_k<<<NB, 256, 0, stream>>>(stage, bo, adj, offs);

    const int gemm_grid = (NN + 63) / 64;       // layer1: 64 rows/block
    const int big_grid  = (NN + 255) / 256;     // layer2/3: 256 rows/block
    for (int l = 0; l < LL - 1; ++l) {
        layer1_k<<<gemm_grid, 512, 0, stream>>>(
            hb, adj, offs, eps, l, wt + (size_t)l * 4096, b1 + l * DD, z1b, stats1, stats2);
        layer2_k<<<big_grid, 256, 0, stream>>>(
            z1b, stats1, g1, be1, l * DD, wt + (size_t)(4 + l) * 4096, b2 + l * DD, z2b, stats2);
        layer3_k<<<big_grid, 256, 0, stream>>>(
            z2b, stats2, gout, beout, l * DD, batch, hb,
            pooled + (size_t)(l + 1) * GG * DD, stats1);
    }
    readout_k<<<(GG * CC + 255) / 256, 256, 0, stream>>>(pooled, Wp, bp, out);
}